// Round 9
// baseline (454.848 us; speedup 1.0000x reference)
//
#include <hip/hip_runtime.h>
#include <hip/hip_bf16.h>

typedef __hip_bfloat16 bf16;
typedef __attribute__((ext_vector_type(8))) short  s16x8;  // 8 bf16 = 4 VGPR (MFMA A/B frag)
typedef __attribute__((ext_vector_type(4))) float  f32x4;  // MFMA C/D frag

static constexpr int S    = 2048;
static constexpr int D    = 4096;
static constexpr int H    = 32;
static constexpr int QL   = 1536;
static constexpr int KVL  = 512;
static constexpr int NOPE = 128;
static constexpr int ROPE = 64;
static constexpr int QKH  = 192;
static constexpr int VH   = 128;
static constexpr int CAT  = 576;
static constexpr int CAT2 = 192;    // absorbed head dim: 128 nope + 64 rope
static constexpr int NCAT = 2112;   // QL + CAT (merged q_a/kv_a GEMM width)
static constexpr float EPS = 1e-6f;

__device__ __forceinline__ void stf(float* p, float v){ *p = v; }
__device__ __forceinline__ void stf(bf16* p, float v){ *p = __float2bfloat16(v); }

__device__ __forceinline__ float wave_sum(float v){
#pragma unroll
  for (int off = 32; off; off >>= 1) v += __shfl_xor(v, off, 64);
  return v;
}

__device__ __forceinline__ void gload16(const bf16* src, unsigned short* dst){
  __builtin_amdgcn_global_load_lds(
      (const __attribute__((address_space(1))) unsigned int*)src,
      (__attribute__((address_space(3))) unsigned int*)dst, 16, 0, 0);
}

// ---------------------------------------------------------------------------
// f32 -> bf16 cast, vectorized
// ---------------------------------------------------------------------------
__global__ __launch_bounds__(256)
void cast_kernel(const float* __restrict__ in, bf16* __restrict__ out, long long n4)
{
  long long i = (long long)blockIdx.x * 256 + threadIdx.x;
  const long long stride = (long long)gridDim.x * 256;
  for (; i < n4; i += stride) {
    float4 v = ((const float4*)in)[i];
    union { bf16 b[4]; uint2 u; } t;
    t.b[0] = __float2bfloat16(v.x); t.b[1] = __float2bfloat16(v.y);
    t.b[2] = __float2bfloat16(v.z); t.b[3] = __float2bfloat16(v.w);
    *(uint2*)(out + i * 4) = t.u;
  }
}

// ---------------------------------------------------------------------------
// f32 add: dst += src (K-split combine for the out GEMM)
// ---------------------------------------------------------------------------
__global__ __launch_bounds__(256)
void add_kernel(float* __restrict__ dst, const float* __restrict__ src, long long n4)
{
  long long i = (long long)blockIdx.x * 256 + threadIdx.x;
  const long long stride = (long long)gridDim.x * 256;
  for (; i < n4; i += stride) {
    float4 a = ((const float4*)dst)[i];
    const float4 b = ((const float4*)src)[i];
    a.x += b.x; a.y += b.y; a.z += b.z; a.w += b.w;
    ((float4*)dst)[i] = a;
  }
}

// ---------------------------------------------------------------------------
// transpose-cast: in f32 [batch][R][C] -> out bf16 [batch][C][R]. 32x32 tiles.
// ---------------------------------------------------------------------------
__global__ __launch_bounds__(256)
void tcast_kernel(const float* __restrict__ in, bf16* __restrict__ out, int R, int C)
{
  const long long b = blockIdx.z;
  in  += b * (long long)R * C;
  out += b * (long long)R * C;
  const int c0 = blockIdx.x * 32, r0 = blockIdx.y * 32;
  __shared__ float t[32][33];
  const int tx = threadIdx.x & 31, ty = threadIdx.x >> 5;
#pragma unroll
  for (int p = 0; p < 4; p++)
    t[ty + p * 8][tx] = in[(long long)(r0 + ty + p * 8) * C + c0 + tx];
  __syncthreads();
#pragma unroll
  for (int p = 0; p < 4; p++)
    out[(long long)(c0 + ty + p * 8) * R + r0 + tx] = __float2bfloat16(t[tx][ty + p * 8]);
}

// ---------------------------------------------------------------------------
// MFMA GEMM v2 (verified): C = A @ B^T, B [N,K] bf16 row-major.
// BM=BN=128, BK=32, 4 waves, global_load_lds w16, XOR-swizzled LDS.
// TRC: store C transposed.  K-split: K = chunk size, sA = sB = chunk col
// offset, sC = partial-buffer offset; blockIdx.z selects the chunk.
// ---------------------------------------------------------------------------
template<typename TC, bool TRC = false>
__global__ __launch_bounds__(256)
void mgemm2(const bf16* __restrict__ A, const bf16* __restrict__ B, TC* __restrict__ C,
            int M, int N, int K, int lda, int ldb, int ldc,
            long long sA, long long sB, long long sC)
{
  A += (long long)blockIdx.z * sA;
  B += (long long)blockIdx.z * sB;
  C += (long long)blockIdx.z * sC;
  __shared__ unsigned short As[128 * 32];
  __shared__ unsigned short Bs[128 * 32];
  const int tid = threadIdx.x;
  const int lane = tid & 63, w = tid >> 6;
  const int l15 = lane & 15, g = lane >> 4;
  const int wr = w >> 1, wc = w & 1;
  const int m0 = blockIdx.y * 128, n0 = blockIdx.x * 128;

  int rA[2], cA[2];
#pragma unroll
  for (int j = 0; j < 2; j++) {
    const int f = j * 256 + tid;
    rA[j] = f >> 2;
    cA[j] = ((f & 3) ^ ((rA[j] >> 1) & 3)) * 8;
  }
  const int swz = ((l15 >> 1) & 3) << 4;
  const int foff = (g * 16) ^ swz;

  f32x4 acc[4][4];
#pragma unroll
  for (int i = 0; i < 4; i++)
#pragma unroll
    for (int j = 0; j < 4; j++) acc[i][j] = (f32x4){0.f, 0.f, 0.f, 0.f};

  for (int k0 = 0; k0 < K; k0 += 32) {
#pragma unroll
    for (int j = 0; j < 2; j++) {
      gload16(A + (long long)(m0 + rA[j]) * lda + k0 + cA[j],
              &As[(j * 256 + w * 64) * 8]);
      const int br = (n0 + rA[j] < N) ? (n0 + rA[j]) : (N - 1);
      gload16(B + (long long)br * ldb + k0 + cA[j],
              &Bs[(j * 256 + w * 64) * 8]);
    }
    __syncthreads();
    s16x8 af[4], bf_[4];
#pragma unroll
    for (int mt = 0; mt < 4; mt++)
      af[mt] = *(const s16x8*)((const char*)As + (wr * 64 + mt * 16 + l15) * 64 + foff);
#pragma unroll
    for (int nt = 0; nt < 4; nt++)
      bf_[nt] = *(const s16x8*)((const char*)Bs + (wc * 64 + nt * 16 + l15) * 64 + foff);
#pragma unroll
    for (int mt = 0; mt < 4; mt++)
#pragma unroll
      for (int nt = 0; nt < 4; nt++)
        acc[mt][nt] = __builtin_amdgcn_mfma_f32_16x16x32_bf16(af[mt], bf_[nt], acc[mt][nt], 0, 0, 0);
    __syncthreads();
  }
#pragma unroll
  for (int mt = 0; mt < 4; mt++)
#pragma unroll
    for (int nt = 0; nt < 4; nt++) {
      const int col = n0 + wc * 64 + nt * 16 + l15;
      if (col < N) {
        const int row0 = m0 + wr * 64 + mt * 16 + g * 4;
        if constexpr (TRC) {
#pragma unroll
          for (int r = 0; r < 4; r++)
            stf(C + (long long)col * ldc + row0 + r, acc[mt][nt][r]);
        } else {
#pragma unroll
          for (int r = 0; r < 4; r++)
            stf(C + (long long)(row0 + r) * ldc + col, acc[mt][nt][r]);
        }
      }
    }
}

// ---------------------------------------------------------------------------
// RMSNorm over SUM of FOUR K-split partials (z-stride poff), N = QL fixed:
// x f32 [rows][ldx] -> bf16 out [rows][QL].  Summed values held in registers
// (6 = QL/256 per thread) so the partials are read exactly once.
// ---------------------------------------------------------------------------
__global__ __launch_bounds__(256)
void rmsnorm_cast_kernel(const float* __restrict__ x, const float* __restrict__ g,
                         bf16* __restrict__ out, int ldx, long long poff)
{
  const int row = blockIdx.x;
  const float* xr = x + (long long)row * ldx;
  float v[6];
  float ss = 0.f;
#pragma unroll
  for (int k = 0; k < 6; k++) {
    const int c = threadIdx.x + (k << 8);
    const float t = xr[c] + xr[c + poff] + xr[c + 2 * poff] + xr[c + 3 * poff];
    v[k] = t; ss += t * t;
  }
  __shared__ float red[4];
  ss = wave_sum(ss);
  if ((threadIdx.x & 63) == 0) red[threadIdx.x >> 6] = ss;
  __syncthreads();
  const float inv = rsqrtf((red[0] + red[1] + red[2] + red[3]) / (float)QL + EPS);
#pragma unroll
  for (int k = 0; k < 6; k++) {
    const int c = threadIdx.x + (k << 8);
    out[(long long)row * QL + c] = __float2bfloat16(v[k] * inv * g[c]);
  }
}

// ---------------------------------------------------------------------------
// kv post over SUM of FOUR K-split partials (row stride ldr, z-stride poff):
//   rmsnorm(kv[:,:512]) + rope(kv[:,512:576]) -> kv_cat bf16 [S][576]
// ---------------------------------------------------------------------------
__global__ __launch_bounds__(256)
void kvpost_kernel(const float* __restrict__ kv_raw, const float* __restrict__ g,
                   const float* __restrict__ cosp, const float* __restrict__ sinp,
                   bf16* __restrict__ kv_cat, int ldr, long long poff)
{
  const int s = blockIdx.x;
  const float* row = kv_raw + (long long)s * ldr;
  float v[2];
  float ss = 0.f;
#pragma unroll
  for (int k = 0; k < 2; k++) {
    const int c = threadIdx.x + (k << 8);
    const float t = row[c] + row[c + poff] + row[c + 2 * poff] + row[c + 3 * poff];
    v[k] = t; ss += t * t;
  }
  __shared__ float red[4];
  float ws_ = wave_sum(ss);
  if ((threadIdx.x & 63) == 0) red[threadIdx.x >> 6] = ws_;
  __syncthreads();
  const float inv = rsqrtf((red[0] + red[1] + red[2] + red[3]) / (float)KVL + EPS);
#pragma unroll
  for (int k = 0; k < 2; k++) {
    const int c = threadIdx.x + (k << 8);
    kv_cat[(long long)s * CAT + c] = __float2bfloat16(v[k] * inv * g[c]);
  }
  if (threadIdx.x < 64) {
    const int r = threadIdx.x;
    const int c = KVL + r;
    const float x = row[c] + row[c + poff] + row[c + 2 * poff] + row[c + 3 * poff];
    const float xp = __shfl_xor(x, 32, 64);
    const float rot = (r < 32) ? -xp : xp;
    kv_cat[(long long)s * CAT + KVL + r] =
        __float2bfloat16(x * cosp[s * ROPE + r] + rot * sinp[s * ROPE + r]);
  }
}

// ---------------------------------------------------------------------------
// q prep: q2[h][s][0:128] = q_raw nope cols; q2[h][s][128:192] = rope(q_rope)
// one wave per (s,h)
// ---------------------------------------------------------------------------
__global__ __launch_bounds__(256)
void qprep_kernel(const bf16* __restrict__ q_raw, const float* __restrict__ cosp,
                  const float* __restrict__ sinp, bf16* __restrict__ q2)
{
  const int wid  = blockIdx.x * 4 + (threadIdx.x >> 6);
  const int lane = threadIdx.x & 63;
  const int s = wid >> 5;
  const int h = wid & 31;
  const bf16* src = q_raw + (long long)s * (H * QKH) + h * QKH;
  bf16* dst = q2 + ((long long)h * S + s) * CAT2;
  // nope copy: 128 bf16 = 64 lanes x 1 uint
  ((unsigned int*)dst)[lane] = ((const unsigned int*)src)[lane];
  // rope
  const float x  = __bfloat162float(src[NOPE + lane]);
  const float xp = __shfl_xor(x, 32, 64);
  const float rot = (lane < 32) ? -xp : xp;
  dst[NOPE + lane] =
      __float2bfloat16(x * cosp[s * ROPE + lane] + rot * sinp[s * ROPE + lane]);
}

// ---------------------------------------------------------------------------
// k rope broadcast: k2[h][s][128+r] = kv_cat[s][512+r] for all heads
// ---------------------------------------------------------------------------
__global__ __launch_bounds__(256)
void krope_bcast(const bf16* __restrict__ kv_cat, bf16* __restrict__ k2)
{
  const int s = blockIdx.x;
  const int h = threadIdx.x >> 3;
  const int i = (threadIdx.x & 7) * 8;
  *(uint4*)(k2 + ((long long)h * S + s) * CAT2 + NOPE + i) =
      *(const uint4*)(kv_cat + (long long)s * CAT + KVL + i);
}

// ---------------------------------------------------------------------------
// MFMA flash attention v13 (verified R4-R8): key+value absorbed, head dim 192,
// cheap overflow-detect softmax.
// ---------------------------------------------------------------------------
__global__ __launch_bounds__(512, 2)
void attn_mfma13(const bf16* __restrict__ q2, const bf16* __restrict__ k2,
                 const bf16* __restrict__ kv_vT, bf16* __restrict__ ctx)
{
  __shared__ unsigned short kkl[2][32 * CAT2];  // 2 x 12,288 B  K tiles (swizzled)
  __shared__ unsigned short vtl[2][128 * 32];   // 2 x  8,192 B  V^T tiles (swizzled)
  __shared__ unsigned short ps[8][16][40];      // 10,240 B per-wave P transpose
  const int tid = threadIdx.x;
  const int bid = blockIdx.x;
  const int h  = bid & 31;
  const int qb = 15 - (bid >> 5);               // heavy blocks dispatched first
  const int w = tid >> 6, lane = tid & 63;
  const int l15 = lane & 15, g = lane >> 4;
  const int wq0 = qb * 128 + w * 16;
  const int rbase = g * 4;
  const float scale = 0.07216878364870322f;     // 1/sqrt(192)

  // K stage sources: 768 chunks (row = 24 x 16B); f -> key r=f/24,
  // global byte col = ((f%24)<<4) ^ ((r&7)<<4)  (same involution as reads)
  const bf16* ksrc[2];
#pragma unroll
  for (int j = 0; j < 2; j++) {
    const int f  = j * 512 + ((j == 1) ? (tid & 255) : tid);
    const int r  = f / 24;
    const int cg = ((f % 24) << 4) ^ ((r & 7) << 4);
    ksrc[j] = k2 + ((long long)h * S + r) * CAT2 + (cg >> 1);
  }
  // V^T stage source: 512 chunks; f=tid -> v-row c=f>>2, key slot swizzled
  const int vc = tid >> 2;
  const bf16* vsrc = kv_vT + (long long)h * VH * S + (long long)vc * S
                   + (((tid & 3) ^ ((vc >> 1) & 3)) * 8);

  auto stage = [&](int buf, int kbase) {
    gload16(ksrc[0] + (long long)kbase * CAT2, &kkl[buf][(w * 64) * 8]);
    if (tid < 256)
      gload16(ksrc[1] + (long long)kbase * CAT2, &kkl[buf][(512 + w * 64) * 8]);
    gload16(vsrc + kbase, &vtl[buf][(w * 64) * 8]);
  };

  // Q fragments: lane holds q-row wq0+l15, col = ch*32 + g*8 + i
  s16x8 qf[6];
  const bf16* qp = q2 + ((long long)h * S + (wq0 + l15)) * CAT2 + g * 8;
#pragma unroll
  for (int ch = 0; ch < 6; ch++) qf[ch] = *(const s16x8*)(qp + ch * 32);

  // all-ones bf16 B-frag for the l row-sum MFMA
  s16x8 ones;
#pragma unroll
  for (int i = 0; i < 8; i++) ones[i] = (short)0x3F80;

  f32x4 acc[8];
#pragma unroll
  for (int nt = 0; nt < 8; nt++) acc[nt] = (f32x4){0.f, 0.f, 0.f, 0.f};
  f32x4 accl = (f32x4){0.f, 0.f, 0.f, 0.f};    // l accumulator (ones-column)
  float mrow[4];
#pragma unroll
  for (int r = 0; r < 4; r++) mrow[r] = -3e38f;

  stage(0, 0);
  __syncthreads();

  const int ntb = 4 * qb + 4;
  int buf = 0;
  for (int t = 0; t < ntb; t++) {
    const int kbase = t * 32;
    if (t + 1 < ntb) stage(buf ^ 1, kbase + 32);   // overlap with compute(t)
    if (kbase <= wq0 + 15) {
      // ---- QK^T: B-frags from swizzled K tile (6 chunks of 32 cols) ----
      f32x4 st0 = (f32x4){0.f,0.f,0.f,0.f}, st1 = (f32x4){0.f,0.f,0.f,0.f};
      const unsigned short* kb0 = &kkl[buf][l15 * CAT2];
      const int rsw = (l15 & 7) << 4;
#pragma unroll
      for (int ch = 0; ch < 6; ch++) {
        const int cb = ((ch * 64 + g * 16) ^ rsw) >> 1;
        s16x8 b0 = *(const s16x8*)(kb0 + cb);
        s16x8 b1 = *(const s16x8*)(kb0 + 16 * CAT2 + cb);
        st0 = __builtin_amdgcn_mfma_f32_16x16x32_bf16(qf[ch], b0, st0, 0, 0, 0);
        st1 = __builtin_amdgcn_mfma_f32_16x16x32_bf16(qf[ch], b1, st1, 0, 0, 0);
      }
      // ---- online softmax: optimistic exp with old max, overflow detect ----
      float p0v[4], p1v[4];
      float pmax = 0.f;
#pragma unroll
      for (int r = 0; r < 4; r++) {
        const int qg = wq0 + rbase + r;
        const bool v0 = (kbase + l15) <= qg, v1 = (kbase + 16 + l15) <= qg;
        const float s0 = st0[r] * scale, s1 = st1[r] * scale;
        const float p0 = v0 ? __expf(s0 - mrow[r]) : 0.f;
        const float p1 = v1 ? __expf(s1 - mrow[r]) : 0.f;
        p0v[r] = p0; p1v[r] = p1;
        pmax = fmaxf(pmax, fmaxf(p0, p1));
      }
      if (__builtin_expect(__any(pmax > 2981.0f), 0)) {   // rare: growth > ~8
#pragma unroll
        for (int r = 0; r < 4; r++) {
          const int qg = wq0 + rbase + r;
          const bool v0 = (kbase + l15) <= qg, v1 = (kbase + 16 + l15) <= qg;
          const float s0 = st0[r] * scale, s1 = st1[r] * scale;
          float tmax = fmaxf(v0 ? s0 : -3e38f, v1 ? s1 : -3e38f);
#pragma unroll
          for (int off = 8; off; off >>= 1) tmax = fmaxf(tmax, __shfl_xor(tmax, off, 64));
          if (tmax > mrow[r] + 8.0f) {
            const float corr = __expf(mrow[r] - tmax);    // 0 on first tile
            mrow[r] = tmax;
#pragma unroll
            for (int nt = 0; nt < 8; nt++) acc[nt][r] *= corr;
            accl[r] *= corr;
            p0v[r] = v0 ? __expf(s0 - mrow[r]) : 0.f;
            p1v[r] = v1 ? __expf(s1 - mrow[r]) : 0.f;
          }
        }
      }
#pragma unroll
      for (int r = 0; r < 4; r++) {
        union { bf16 b; unsigned short u; } c0, c1;
        c0.b = __float2bfloat16(p0v[r]); c1.b = __float2bfloat16(p1v[r]);
        ps[w][rbase + r][l15]      = c0.u;
        ps[w][rbase + r][16 + l15] = c1.u;
      }
      asm volatile("" ::: "memory");   // order ps stores before reads (per-wave)
      // ---- PV: V^T from swizzled LDS (conflict-free) + ones-column for l ----
      s16x8 pa = *(const s16x8*)&ps[w][l15][g * 8];  // A-frag: row=l15, key=g*8+i
      const unsigned short* vt = &vtl[buf][l15 * 32 + ((g * 8) ^ (((l15 >> 1) & 3) * 8))];
#pragma unroll
      for (int nt = 0; nt < 8; nt++) {
        s16x8 bv = *(const s16x8*)(vt + nt * 512);
        acc[nt] = __builtin_amdgcn_mfma_f32_16x16x32_bf16(pa, bv, acc[nt], 0, 0, 0);
      }
      accl = __builtin_amdgcn_mfma_f32_16x16x32_bf16(pa, ones, accl, 0, 0, 0);
    }
    __syncthreads();   // drains stage(t+1) loads + all waves done with buf
    buf ^= 1;
  }

  // ---- epilogue: normalize by l, store ctx[s][h*128+v] bf16 ----
#pragma unroll
  for (int r = 0; r < 4; r++) {
    const float inv = 1.f / accl[r];
    bf16* op = ctx + (long long)(wq0 + rbase + r) * (H * VH) + h * VH + l15;
#pragma unroll
    for (int nt = 0; nt < 8; nt++) op[nt * 16] = __float2bfloat16(acc[nt][r] * inv);
  }
}

// ---------------------------------------------------------------------------
extern "C" void kernel_launch(void* const* d_in, const int* in_sizes, int n_in,
                              void* d_out, int out_size, void* d_ws, size_t ws_size,
                              hipStream_t stream)
{
  const float* h2     = (const float*)d_in[0];
  const float* cosp   = (const float*)d_in[1];
  const float* sinp   = (const float*)d_in[2];
  const float* w_q_a  = (const float*)d_in[3];
  const float* g_q_a  = (const float*)d_in[4];
  const float* w_q_b  = (const float*)d_in[5];
  const float* w_kv_a = (const float*)d_in[6];
  const float* g_kv_a = (const float*)d_in[7];
  const float* w_uk_t = (const float*)d_in[8];
  const float* w_uv   = (const float*)d_in[9];
  const float* w_o    = (const float*)d_in[10];
  float* out = (float*)d_out;

  // ---- workspace layout (lifetime-aliased; audited R8) ----
  char* ws = (char*)d_ws;
  bf16* wukb   = (bf16*)(ws);                          // 4,194,304  [H][NOPE][KVL]
  bf16* wuv_t  = (bf16*)(ws + 4194304);                // 4,194,304  [H][VH][KVL]
  bf16* kv_cat = (bf16*)(ws + 8388608);                // 2,359,296
  char* X = ws + 13107200;                             // 75,497,472
  char* Y = X + 75497472;                              // 67,108,864
  // X: qkv_p [4][2048][2112] f32 (69,206,016; dead after rmsnorm+kvpost), then:
  float* qkv_p = (float*)(X);
  bf16*  wo_b  = (bf16*)(X);                           // 33,554,432 (after kvpost)
  bf16*  q2    = (bf16*)(X + 33554432);                // 25,165,824 -> 58,720,256
  bf16*  ctx   = (bf16*)(X + 58720256);                // 16,777,216 -> 75,497,472
  // Y: staged lifetimes
  bf16*  hb     = (bf16*)(Y);                          // 16,777,216 (dead after qkv GEMM)
  bf16*  wcat_b = (bf16*)(Y + 16777216);               // 17,301,504 -> 34,078,720 (dead after qkv)
  bf16*  wqb_b  = (bf16*)(Y);                          // 18,874,368 (cast after qkv, over hb)
  bf16*  q_a_bf = (bf16*)(Y + 18874368);               // 6,291,456 -> 25,165,824
  bf16*  q_raw  = (bf16*)(Y + 25165824);               // 25,165,824 -> 50,331,648 (over dead wcat)
  bf16*  k2     = (bf16*)(Y);                          // 25,165,824 (after q_b GEMM)
  bf16*  kv_vT  = (bf16*)(Y + 50331648);               // 16,777,216 -> 67,108,864
  float* out_p1 = (float*)(Y);                         // 33,554,432 (after attn)

  // ---- early casts ----
  cast_kernel<<<1024, 256, 0, stream>>>(h2,     hb,     (long long)S * D / 4);
  cast_kernel<<<1024, 256, 0, stream>>>(w_q_a,  wcat_b, (long long)QL * D / 4);
  cast_kernel<<<1024, 256, 0, stream>>>(w_kv_a, wcat_b + (long long)QL * D, (long long)CAT * D / 4);
  cast_kernel<<<1024, 256, 0, stream>>>(w_uk_t, wukb,   (long long)H * NOPE * KVL / 4);
  tcast_kernel<<<dim3(VH / 32, KVL / 32, H), 256, 0, stream>>>(w_uv, wuv_t, KVL, VH);

  // 1+4 merged: qkv partials = hb @ wcat_b^T, K-split z=4
  //   (1088 blocks, 4.25/CU -- the reference-GEMM occupancy; partials summed
  //    for free in rmsnorm/kvpost)
  mgemm2<float><<<dim3(17, S / 128, 4), 256, 0, stream>>>(
      hb, wcat_b, qkv_p, S, NCAT, D / 4, D, D, NCAT,
      (long long)(D / 4), (long long)(D / 4), (long long)S * NCAT);
  // cast w_q_b now (hb dead; region reused)
  cast_kernel<<<1024, 256, 0, stream>>>(w_q_b, wqb_b, (long long)H * QKH * QL / 4);
  // 2. rmsnorm over 4-partial sum (first 1536 cols) -> bf16
  rmsnorm_cast_kernel<<<dim3(S), 256, 0, stream>>>(
      qkv_p, g_q_a, q_a_bf, NCAT, (long long)S * NCAT);
  // 3. q = q_a @ w_q_b^T -> bf16
  mgemm2<bf16><<<dim3(H * QKH / 128, S / 128, 1), 256, 0, stream>>>(
      q_a_bf, wqb_b, q_raw, S, H * QKH, QL, QL, QL, H * QKH, 0, 0, 0);
  // 5. kv post over 4-partial sum (cols 1536..2111) -> kv_cat
  kvpost_kernel<<<dim3(S), 256, 0, stream>>>(
      qkv_p + QL, g_kv_a, cosp, sinp, kv_cat, NCAT, (long long)S * NCAT);
  // cast w_o (qkv_p dead after rmsnorm+kvpost; region reused)
  cast_kernel<<<1024, 256, 0, stream>>>(w_o, wo_b, (long long)D * H * VH / 4);
  // 5b. value-absorb: kv_vT[h] = (kv_c @ w_uv[h])^T  -> bf16 [h][128][S]
  mgemm2<bf16, true><<<dim3(VH / 128, S / 128, H), 256, 0, stream>>>(
      kv_cat, wuv_t, kv_vT, S, VH, KVL, CAT, KVL, S,
      0, (long long)VH * KVL, (long long)VH * S);
  // 6. q prep (nope copy + rope) -> q2 [h][s][192]  (q_raw dead after this)
  qprep_kernel<<<dim3(S * H / 4), 256, 0, stream>>>(q_raw, cosp, sinp, q2);
  // 7. key-absorb: k2[h][...,0:128] = kv_c @ w_uk[h]^T  (over dead wqb_b/q_a_bf)
  mgemm2<bf16><<<dim3(1, S / 128, H), 256, 0, stream>>>(
      kv_cat, wukb, k2, S, NOPE, KVL, CAT, KVL, CAT2,
      0, (long long)NOPE * KVL, (long long)S * CAT2);
  // 7b. k rope broadcast -> k2[h][...,128:192]
  krope_bcast<<<dim3(S), 256, 0, stream>>>(kv_cat, k2);
  // 8. attention (key+value absorbed, head dim 192) -> ctx bf16 [s][h*128+v]
  attn_mfma13<<<dim3(512), dim3(512), 0, stream>>>(q2, k2, kv_vT, ctx);
  // 10. out = ctx @ w_o^T -> f32, K-split z=2 (1024 blocks, 4/CU;
  //     z=0 -> out, z=1 -> out_p1 via flat-address sC offset, verified R6)
  const long long ooff = (long long)(out_p1 - out);
  mgemm2<float><<<dim3(D / 128, S / 128, 2), 256, 0, stream>>>(
      ctx, wo_b, out, S, D, D / 2, D, D, D,
      (long long)(D / 2), (long long)(D / 2), ooff);
  // 10b. combine: out += out_p1
  add_kernel<<<1024, 256, 0, stream>>>(out, out_p1, (long long)S * D / 4);

  (void)in_sizes; (void)n_in; (void)out_size; (void)ws_size;
}

// Round 10
// 417.614 us; speedup vs baseline: 1.0892x; 1.0892x over previous
//
#include <hip/hip_runtime.h>
#include <hip/hip_bf16.h>

typedef __hip_bfloat16 bf16;
typedef __attribute__((ext_vector_type(8))) short  s16x8;  // 8 bf16 = 4 VGPR (MFMA A/B frag)
typedef __attribute__((ext_vector_type(4))) float  f32x4;  // MFMA C/D frag

static constexpr int S    = 2048;
static constexpr int D    = 4096;
static constexpr int H    = 32;
static constexpr int QL   = 1536;
static constexpr int KVL  = 512;
static constexpr int NOPE = 128;
static constexpr int ROPE = 64;
static constexpr int QKH  = 192;
static constexpr int VH   = 128;
static constexpr int CAT  = 576;
static constexpr int CAT2 = 192;    // absorbed head dim: 128 nope + 64 rope
static constexpr int NCAT = 2112;   // QL + CAT (merged q_a/kv_a GEMM width)
static constexpr float EPS = 1e-6f;

__device__ __forceinline__ void stf(float* p, float v){ *p = v; }
__device__ __forceinline__ void stf(bf16* p, float v){ *p = __float2bfloat16(v); }

__device__ __forceinline__ float wave_sum(float v){
#pragma unroll
  for (int off = 32; off; off >>= 1) v += __shfl_xor(v, off, 64);
  return v;
}

__device__ __forceinline__ void gload16(const bf16* src, unsigned short* dst){
  __builtin_amdgcn_global_load_lds(
      (const __attribute__((address_space(1))) unsigned int*)src,
      (__attribute__((address_space(3))) unsigned int*)dst, 16, 0, 0);
}

// ---------------------------------------------------------------------------
// f32 -> bf16 cast, vectorized
// ---------------------------------------------------------------------------
__global__ __launch_bounds__(256)
void cast_kernel(const float* __restrict__ in, bf16* __restrict__ out, long long n4)
{
  long long i = (long long)blockIdx.x * 256 + threadIdx.x;
  const long long stride = (long long)gridDim.x * 256;
  for (; i < n4; i += stride) {
    float4 v = ((const float4*)in)[i];
    union { bf16 b[4]; uint2 u; } t;
    t.b[0] = __float2bfloat16(v.x); t.b[1] = __float2bfloat16(v.y);
    t.b[2] = __float2bfloat16(v.z); t.b[3] = __float2bfloat16(v.w);
    *(uint2*)(out + i * 4) = t.u;
  }
}

// ---------------------------------------------------------------------------
// f32 add: dst += src (K-split combine for the out GEMM)
// ---------------------------------------------------------------------------
__global__ __launch_bounds__(256)
void add_kernel(float* __restrict__ dst, const float* __restrict__ src, long long n4)
{
  long long i = (long long)blockIdx.x * 256 + threadIdx.x;
  const long long stride = (long long)gridDim.x * 256;
  for (; i < n4; i += stride) {
    float4 a = ((const float4*)dst)[i];
    const float4 b = ((const float4*)src)[i];
    a.x += b.x; a.y += b.y; a.z += b.z; a.w += b.w;
    ((float4*)dst)[i] = a;
  }
}

// ---------------------------------------------------------------------------
// transpose-cast: in f32 [batch][R][C] -> out bf16 [batch][C][R]. 32x32 tiles.
// ---------------------------------------------------------------------------
__global__ __launch_bounds__(256)
void tcast_kernel(const float* __restrict__ in, bf16* __restrict__ out, int R, int C)
{
  const long long b = blockIdx.z;
  in  += b * (long long)R * C;
  out += b * (long long)R * C;
  const int c0 = blockIdx.x * 32, r0 = blockIdx.y * 32;
  __shared__ float t[32][33];
  const int tx = threadIdx.x & 31, ty = threadIdx.x >> 5;
#pragma unroll
  for (int p = 0; p < 4; p++)
    t[ty + p * 8][tx] = in[(long long)(r0 + ty + p * 8) * C + c0 + tx];
  __syncthreads();
#pragma unroll
  for (int p = 0; p < 4; p++)
    out[(long long)(c0 + ty + p * 8) * R + r0 + tx] = __float2bfloat16(t[tx][ty + p * 8]);
}

// ---------------------------------------------------------------------------
// MFMA GEMM v2 (verified): C = A @ B^T, B [N,K] bf16 row-major.
// BM=BN=128, BK=32, 4 waves, global_load_lds w16, XOR-swizzled LDS.
// ---------------------------------------------------------------------------
template<typename TC, bool TRC = false>
__global__ __launch_bounds__(256)
void mgemm2(const bf16* __restrict__ A, const bf16* __restrict__ B, TC* __restrict__ C,
            int M, int N, int K, int lda, int ldb, int ldc,
            long long sA, long long sB, long long sC)
{
  A += (long long)blockIdx.z * sA;
  B += (long long)blockIdx.z * sB;
  C += (long long)blockIdx.z * sC;
  __shared__ unsigned short As[128 * 32];
  __shared__ unsigned short Bs[128 * 32];
  const int tid = threadIdx.x;
  const int lane = tid & 63, w = tid >> 6;
  const int l15 = lane & 15, g = lane >> 4;
  const int wr = w >> 1, wc = w & 1;
  const int m0 = blockIdx.y * 128, n0 = blockIdx.x * 128;

  int rA[2], cA[2];
#pragma unroll
  for (int j = 0; j < 2; j++) {
    const int f = j * 256 + tid;
    rA[j] = f >> 2;
    cA[j] = ((f & 3) ^ ((rA[j] >> 1) & 3)) * 8;
  }
  const int swz = ((l15 >> 1) & 3) << 4;
  const int foff = (g * 16) ^ swz;

  f32x4 acc[4][4];
#pragma unroll
  for (int i = 0; i < 4; i++)
#pragma unroll
    for (int j = 0; j < 4; j++) acc[i][j] = (f32x4){0.f, 0.f, 0.f, 0.f};

  for (int k0 = 0; k0 < K; k0 += 32) {
#pragma unroll
    for (int j = 0; j < 2; j++) {
      gload16(A + (long long)(m0 + rA[j]) * lda + k0 + cA[j],
              &As[(j * 256 + w * 64) * 8]);
      const int br = (n0 + rA[j] < N) ? (n0 + rA[j]) : (N - 1);
      gload16(B + (long long)br * ldb + k0 + cA[j],
              &Bs[(j * 256 + w * 64) * 8]);
    }
    __syncthreads();
    s16x8 af[4], bf_[4];
#pragma unroll
    for (int mt = 0; mt < 4; mt++)
      af[mt] = *(const s16x8*)((const char*)As + (wr * 64 + mt * 16 + l15) * 64 + foff);
#pragma unroll
    for (int nt = 0; nt < 4; nt++)
      bf_[nt] = *(const s16x8*)((const char*)Bs + (wc * 64 + nt * 16 + l15) * 64 + foff);
#pragma unroll
    for (int mt = 0; mt < 4; mt++)
#pragma unroll
      for (int nt = 0; nt < 4; nt++)
        acc[mt][nt] = __builtin_amdgcn_mfma_f32_16x16x32_bf16(af[mt], bf_[nt], acc[mt][nt], 0, 0, 0);
    __syncthreads();
  }
#pragma unroll
  for (int mt = 0; mt < 4; mt++)
#pragma unroll
    for (int nt = 0; nt < 4; nt++) {
      const int col = n0 + wc * 64 + nt * 16 + l15;
      if (col < N) {
        const int row0 = m0 + wr * 64 + mt * 16 + g * 4;
        if constexpr (TRC) {
#pragma unroll
          for (int r = 0; r < 4; r++)
            stf(C + (long long)col * ldc + row0 + r, acc[mt][nt][r]);
        } else {
#pragma unroll
          for (int r = 0; r < 4; r++)
            stf(C + (long long)(row0 + r) * ldc + col, acc[mt][nt][r]);
        }
      }
    }
}

// ---------------------------------------------------------------------------
// MFMA GEMM v3: 256x256 tile, BK=64, 8 waves, counted-vmcnt deep pipeline.
//   Breaks the 2-phase ~607 TF ceiling (m233): raw s_barrier + inline-asm
//   s_waitcnt vmcnt(8) keeps the NEXT tile's 8 global_load_lds in flight
//   ACROSS the barrier (T4) -- loads get a full tile's MFMA time (~600 cyc)
//   to land instead of a vmcnt(0) drain every K-step.
//   LDS layout: [256 rows][64 cols] bf16, row = 8 x 16B chunks, physical
//   chunk = logical ^ (row&7) (per-quarter-wave 2-way on ds_read = free);
//   staging pre-swizzles the GLOBAL source col (rule #21), LDS dest linear.
//   Wave (wr=w>>2, wc=w&3) owns C rows [wr*128,+128) x cols [wc*64,+64):
//   each wave reads ONE A-half and ONE B-quarter per tile; 64 MFMA/tile.
//   N-guard: B row clamped, C col guarded (N=2112 tail).  K-split via z.
// ---------------------------------------------------------------------------
template<typename TC>
__global__ __launch_bounds__(512, 2)
void mgemm3(const bf16* __restrict__ A, const bf16* __restrict__ B, TC* __restrict__ C,
            int M, int N, int K, int lda, int ldb, int ldc,
            long long sA, long long sB, long long sC)
{
  A += (long long)blockIdx.z * sA;
  B += (long long)blockIdx.z * sB;
  C += (long long)blockIdx.z * sC;
  __shared__ unsigned short As[2][256 * 64];   // 2 x 32 KB
  __shared__ unsigned short Bs[2][256 * 64];   // 2 x 32 KB
  const int tid = threadIdx.x;
  const int w = tid >> 6;
  const int lane = tid & 63;
  const int l15 = lane & 15, g = lane >> 4;
  const int wr = w >> 2, wc = w & 3;
  const int m0 = blockIdx.y * 256, n0 = blockIdx.x * 256;

  // staging sources: 8 gloads/thread/tile (4 A + 4 B), source col pre-swizzled
  const bf16* asrc[4];
  const bf16* bsrc[4];
#pragma unroll
  for (int j = 0; j < 4; j++) {
    const int f = j * 512 + tid;
    const int row = f >> 3;                 // 0..255
    const int cg = ((f & 7) ^ (row & 7)) * 8;
    asrc[j] = A + (long long)(m0 + row) * lda + cg;
    int br = n0 + row; if (br >= N) br = N - 1;
    bsrc[j] = B + (long long)br * ldb + cg;
  }

  auto stage = [&](int b, int k0) {
#pragma unroll
    for (int j = 0; j < 4; j++) {
      gload16(asrc[j] + k0, &As[b][(j * 512 + w * 64) * 8]);
      gload16(bsrc[j] + k0, &Bs[b][(j * 512 + w * 64) * 8]);
    }
  };

  f32x4 acc[8][4];
#pragma unroll
  for (int i = 0; i < 8; i++)
#pragma unroll
    for (int j = 0; j < 4; j++) acc[i][j] = (f32x4){0.f, 0.f, 0.f, 0.f};

  const int ntk = K >> 6;                   // K-tiles of 64
  stage(0, 0);                              // prologue: tile 0 -> buf 0

  for (int t = 0; t < ntk; ++t) {
    const int b = t & 1;
    asm volatile("" ::: "memory");
    __builtin_amdgcn_s_barrier();           // all waves done reading buf b^1 (tile t-1)
    if (t + 1 < ntk) {
      stage(b ^ 1, (t + 1) << 6);           // issue tile t+1 -> buf b^1
      asm volatile("s_waitcnt vmcnt(8)" ::: "memory");   // tile t's 8 landed; t+1's stay in flight
    } else {
      asm volatile("s_waitcnt vmcnt(0)" ::: "memory");   // final tile: drain
    }
    __builtin_amdgcn_s_barrier();           // all waves' tile-t loads visible
    asm volatile("" ::: "memory");

    const unsigned short* Ab = &As[b][(wr * 128 + l15) * 64];
    const unsigned short* Bb = &Bs[b][(wc * 64 + l15) * 64];
    const int swz = l15 & 7;
#pragma unroll
    for (int kk = 0; kk < 2; ++kk) {
      const int co = (((kk * 4 + g) ^ swz) * 8);
      s16x8 a[8], bb[4];
#pragma unroll
      for (int mt = 0; mt < 8; mt++)
        a[mt] = *(const s16x8*)(Ab + mt * 1024 + co);
#pragma unroll
      for (int nt = 0; nt < 4; nt++)
        bb[nt] = *(const s16x8*)(Bb + nt * 1024 + co);
      __builtin_amdgcn_s_setprio(1);
#pragma unroll
      for (int mt = 0; mt < 8; mt++)
#pragma unroll
        for (int nt = 0; nt < 4; nt++)
          acc[mt][nt] = __builtin_amdgcn_mfma_f32_16x16x32_bf16(a[mt], bb[nt], acc[mt][nt], 0, 0, 0);
      __builtin_amdgcn_s_setprio(0);
    }
  }

  // epilogue: C write (rows always valid: M % 256 == 0; cols guarded)
#pragma unroll
  for (int mt = 0; mt < 8; mt++)
#pragma unroll
    for (int nt = 0; nt < 4; nt++) {
      const int col = n0 + wc * 64 + nt * 16 + l15;
      if (col < N) {
        const int row0 = m0 + wr * 128 + mt * 16 + g * 4;
#pragma unroll
        for (int r = 0; r < 4; r++)
          stf(C + (long long)(row0 + r) * ldc + col, acc[mt][nt][r]);
      }
    }
}

// ---------------------------------------------------------------------------
// RMSNorm over SUM of FOUR K-split partials (z-stride poff), N = QL fixed.
// ---------------------------------------------------------------------------
__global__ __launch_bounds__(256)
void rmsnorm_cast_kernel(const float* __restrict__ x, const float* __restrict__ g,
                         bf16* __restrict__ out, int ldx, long long poff)
{
  const int row = blockIdx.x;
  const float* xr = x + (long long)row * ldx;
  float v[6];
  float ss = 0.f;
#pragma unroll
  for (int k = 0; k < 6; k++) {
    const int c = threadIdx.x + (k << 8);
    const float t = xr[c] + xr[c + poff] + xr[c + 2 * poff] + xr[c + 3 * poff];
    v[k] = t; ss += t * t;
  }
  __shared__ float red[4];
  ss = wave_sum(ss);
  if ((threadIdx.x & 63) == 0) red[threadIdx.x >> 6] = ss;
  __syncthreads();
  const float inv = rsqrtf((red[0] + red[1] + red[2] + red[3]) / (float)QL + EPS);
#pragma unroll
  for (int k = 0; k < 6; k++) {
    const int c = threadIdx.x + (k << 8);
    out[(long long)row * QL + c] = __float2bfloat16(v[k] * inv * g[c]);
  }
}

// ---------------------------------------------------------------------------
// kv post over SUM of FOUR K-split partials (row stride ldr, z-stride poff).
// ---------------------------------------------------------------------------
__global__ __launch_bounds__(256)
void kvpost_kernel(const float* __restrict__ kv_raw, const float* __restrict__ g,
                   const float* __restrict__ cosp, const float* __restrict__ sinp,
                   bf16* __restrict__ kv_cat, int ldr, long long poff)
{
  const int s = blockIdx.x;
  const float* row = kv_raw + (long long)s * ldr;
  float v[2];
  float ss = 0.f;
#pragma unroll
  for (int k = 0; k < 2; k++) {
    const int c = threadIdx.x + (k << 8);
    const float t = row[c] + row[c + poff] + row[c + 2 * poff] + row[c + 3 * poff];
    v[k] = t; ss += t * t;
  }
  __shared__ float red[4];
  float ws_ = wave_sum(ss);
  if ((threadIdx.x & 63) == 0) red[threadIdx.x >> 6] = ws_;
  __syncthreads();
  const float inv = rsqrtf((red[0] + red[1] + red[2] + red[3]) / (float)KVL + EPS);
#pragma unroll
  for (int k = 0; k < 2; k++) {
    const int c = threadIdx.x + (k << 8);
    kv_cat[(long long)s * CAT + c] = __float2bfloat16(v[k] * inv * g[c]);
  }
  if (threadIdx.x < 64) {
    const int r = threadIdx.x;
    const int c = KVL + r;
    const float x = row[c] + row[c + poff] + row[c + 2 * poff] + row[c + 3 * poff];
    const float xp = __shfl_xor(x, 32, 64);
    const float rot = (r < 32) ? -xp : xp;
    kv_cat[(long long)s * CAT + KVL + r] =
        __float2bfloat16(x * cosp[s * ROPE + r] + rot * sinp[s * ROPE + r]);
  }
}

// ---------------------------------------------------------------------------
// q prep: q2[h][s][0:128] = q_raw nope cols; q2[h][s][128:192] = rope(q_rope)
// ---------------------------------------------------------------------------
__global__ __launch_bounds__(256)
void qprep_kernel(const bf16* __restrict__ q_raw, const float* __restrict__ cosp,
                  const float* __restrict__ sinp, bf16* __restrict__ q2)
{
  const int wid  = blockIdx.x * 4 + (threadIdx.x >> 6);
  const int lane = threadIdx.x & 63;
  const int s = wid >> 5;
  const int h = wid & 31;
  const bf16* src = q_raw + (long long)s * (H * QKH) + h * QKH;
  bf16* dst = q2 + ((long long)h * S + s) * CAT2;
  ((unsigned int*)dst)[lane] = ((const unsigned int*)src)[lane];
  const float x  = __bfloat162float(src[NOPE + lane]);
  const float xp = __shfl_xor(x, 32, 64);
  const float rot = (lane < 32) ? -xp : xp;
  dst[NOPE + lane] =
      __float2bfloat16(x * cosp[s * ROPE + lane] + rot * sinp[s * ROPE + lane]);
}

// ---------------------------------------------------------------------------
// k rope broadcast: k2[h][s][128+r] = kv_cat[s][512+r] for all heads
// ---------------------------------------------------------------------------
__global__ __launch_bounds__(256)
void krope_bcast(const bf16* __restrict__ kv_cat, bf16* __restrict__ k2)
{
  const int s = blockIdx.x;
  const int h = threadIdx.x >> 3;
  const int i = (threadIdx.x & 7) * 8;
  *(uint4*)(k2 + ((long long)h * S + s) * CAT2 + NOPE + i) =
      *(const uint4*)(kv_cat + (long long)s * CAT + KVL + i);
}

// ---------------------------------------------------------------------------
// MFMA flash attention v13 (verified R4-R9): key+value absorbed, head dim 192,
// cheap overflow-detect softmax.
// ---------------------------------------------------------------------------
__global__ __launch_bounds__(512, 2)
void attn_mfma13(const bf16* __restrict__ q2, const bf16* __restrict__ k2,
                 const bf16* __restrict__ kv_vT, bf16* __restrict__ ctx)
{
  __shared__ unsigned short kkl[2][32 * CAT2];  // 2 x 12,288 B  K tiles (swizzled)
  __shared__ unsigned short vtl[2][128 * 32];   // 2 x  8,192 B  V^T tiles (swizzled)
  __shared__ unsigned short ps[8][16][40];      // 10,240 B per-wave P transpose
  const int tid = threadIdx.x;
  const int bid = blockIdx.x;
  const int h  = bid & 31;
  const int qb = 15 - (bid >> 5);               // heavy blocks dispatched first
  const int w = tid >> 6, lane = tid & 63;
  const int l15 = lane & 15, g = lane >> 4;
  const int wq0 = qb * 128 + w * 16;
  const int rbase = g * 4;
  const float scale = 0.07216878364870322f;     // 1/sqrt(192)

  const bf16* ksrc[2];
#pragma unroll
  for (int j = 0; j < 2; j++) {
    const int f  = j * 512 + ((j == 1) ? (tid & 255) : tid);
    const int r  = f / 24;
    const int cg = ((f % 24) << 4) ^ ((r & 7) << 4);
    ksrc[j] = k2 + ((long long)h * S + r) * CAT2 + (cg >> 1);
  }
  const int vc = tid >> 2;
  const bf16* vsrc = kv_vT + (long long)h * VH * S + (long long)vc * S
                   + (((tid & 3) ^ ((vc >> 1) & 3)) * 8);

  auto stage = [&](int buf, int kbase) {
    gload16(ksrc[0] + (long long)kbase * CAT2, &kkl[buf][(w * 64) * 8]);
    if (tid < 256)
      gload16(ksrc[1] + (long long)kbase * CAT2, &kkl[buf][(512 + w * 64) * 8]);
    gload16(vsrc + kbase, &vtl[buf][(w * 64) * 8]);
  };

  s16x8 qf[6];
  const bf16* qp = q2 + ((long long)h * S + (wq0 + l15)) * CAT2 + g * 8;
#pragma unroll
  for (int ch = 0; ch < 6; ch++) qf[ch] = *(const s16x8*)(qp + ch * 32);

  s16x8 ones;
#pragma unroll
  for (int i = 0; i < 8; i++) ones[i] = (short)0x3F80;

  f32x4 acc[8];
#pragma unroll
  for (int nt = 0; nt < 8; nt++) acc[nt] = (f32x4){0.f, 0.f, 0.f, 0.f};
  f32x4 accl = (f32x4){0.f, 0.f, 0.f, 0.f};
  float mrow[4];
#pragma unroll
  for (int r = 0; r < 4; r++) mrow[r] = -3e38f;

  stage(0, 0);
  __syncthreads();

  const int ntb = 4 * qb + 4;
  int buf = 0;
  for (int t = 0; t < ntb; t++) {
    const int kbase = t * 32;
    if (t + 1 < ntb) stage(buf ^ 1, kbase + 32);
    if (kbase <= wq0 + 15) {
      f32x4 st0 = (f32x4){0.f,0.f,0.f,0.f}, st1 = (f32x4){0.f,0.f,0.f,0.f};
      const unsigned short* kb0 = &kkl[buf][l15 * CAT2];
      const int rsw = (l15 & 7) << 4;
#pragma unroll
      for (int ch = 0; ch < 6; ch++) {
        const int cb = ((ch * 64 + g * 16) ^ rsw) >> 1;
        s16x8 b0 = *(const s16x8*)(kb0 + cb);
        s16x8 b1 = *(const s16x8*)(kb0 + 16 * CAT2 + cb);
        st0 = __builtin_amdgcn_mfma_f32_16x16x32_bf16(qf[ch], b0, st0, 0, 0, 0);
        st1 = __builtin_amdgcn_mfma_f32_16x16x32_bf16(qf[ch], b1, st1, 0, 0, 0);
      }
      float p0v[4], p1v[4];
      float pmax = 0.f;
#pragma unroll
      for (int r = 0; r < 4; r++) {
        const int qg = wq0 + rbase + r;
        const bool v0 = (kbase + l15) <= qg, v1 = (kbase + 16 + l15) <= qg;
        const float s0 = st0[r] * scale, s1 = st1[r] * scale;
        const float p0 = v0 ? __expf(s0 - mrow[r]) : 0.f;
        const float p1 = v1 ? __expf(s1 - mrow[r]) : 0.f;
        p0v[r] = p0; p1v[r] = p1;
        pmax = fmaxf(pmax, fmaxf(p0, p1));
      }
      if (__builtin_expect(__any(pmax > 2981.0f), 0)) {
#pragma unroll
        for (int r = 0; r < 4; r++) {
          const int qg = wq0 + rbase + r;
          const bool v0 = (kbase + l15) <= qg, v1 = (kbase + 16 + l15) <= qg;
          const float s0 = st0[r] * scale, s1 = st1[r] * scale;
          float tmax = fmaxf(v0 ? s0 : -3e38f, v1 ? s1 : -3e38f);
#pragma unroll
          for (int off = 8; off; off >>= 1) tmax = fmaxf(tmax, __shfl_xor(tmax, off, 64));
          if (tmax > mrow[r] + 8.0f) {
            const float corr = __expf(mrow[r] - tmax);
            mrow[r] = tmax;
#pragma unroll
            for (int nt = 0; nt < 8; nt++) acc[nt][r] *= corr;
            accl[r] *= corr;
            p0v[r] = v0 ? __expf(s0 - mrow[r]) : 0.f;
            p1v[r] = v1 ? __expf(s1 - mrow[r]) : 0.f;
          }
        }
      }
#pragma unroll
      for (int r = 0; r < 4; r++) {
        union { bf16 b; unsigned short u; } c0, c1;
        c0.b = __float2bfloat16(p0v[r]); c1.b = __float2bfloat16(p1v[r]);
        ps[w][rbase + r][l15]      = c0.u;
        ps[w][rbase + r][16 + l15] = c1.u;
      }
      asm volatile("" ::: "memory");
      s16x8 pa = *(const s16x8*)&ps[w][l15][g * 8];
      const unsigned short* vt = &vtl[buf][l15 * 32 + ((g * 8) ^ (((l15 >> 1) & 3) * 8))];
#pragma unroll
      for (int nt = 0; nt < 8; nt++) {
        s16x8 bv = *(const s16x8*)(vt + nt * 512);
        acc[nt] = __builtin_amdgcn_mfma_f32_16x16x32_bf16(pa, bv, acc[nt], 0, 0, 0);
      }
      accl = __builtin_amdgcn_mfma_f32_16x16x32_bf16(pa, ones, accl, 0, 0, 0);
    }
    __syncthreads();
    buf ^= 1;
  }

#pragma unroll
  for (int r = 0; r < 4; r++) {
    const float inv = 1.f / accl[r];
    bf16* op = ctx + (long long)(wq0 + rbase + r) * (H * VH) + h * VH + l15;
#pragma unroll
    for (int nt = 0; nt < 8; nt++) op[nt * 16] = __float2bfloat16(acc[nt][r] * inv);
  }
}

// ---------------------------------------------------------------------------
extern "C" void kernel_launch(void* const* d_in, const int* in_sizes, int n_in,
                              void* d_out, int out_size, void* d_ws, size_t ws_size,
                              hipStream_t stream)
{
  const float* h2     = (const float*)d_in[0];
  const float* cosp   = (const float*)d_in[1];
  const float* sinp   = (const float*)d_in[2];
  const float* w_q_a  = (const float*)d_in[3];
  const float* g_q_a  = (const float*)d_in[4];
  const float* w_q_b  = (const float*)d_in[5];
  const float* w_kv_a = (const float*)d_in[6];
  const float* g_kv_a = (const float*)d_in[7];
  const float* w_uk_t = (const float*)d_in[8];
  const float* w_uv   = (const float*)d_in[9];
  const float* w_o    = (const float*)d_in[10];
  float* out = (float*)d_out;

  // ---- workspace layout (identical to R9, which passed) ----
  char* ws = (char*)d_ws;
  bf16* wukb   = (bf16*)(ws);                          // 4,194,304  [H][NOPE][KVL]
  bf16* wuv_t  = (bf16*)(ws + 4194304);                // 4,194,304  [H][VH][KVL]
  bf16* kv_cat = (bf16*)(ws + 8388608);                // 2,359,296
  char* X = ws + 13107200;                             // 75,497,472
  char* Y = X + 75497472;                              // 67,108,864
  float* qkv_p = (float*)(X);                          // [4][2048][2112] f32 (dead after rmsnorm+kvpost)
  bf16*  wo_b  = (bf16*)(X);                           // 33,554,432 (after kvpost)
  bf16*  q2    = (bf16*)(X + 33554432);                // 25,165,824 -> 58,720,256
  bf16*  ctx   = (bf16*)(X + 58720256);                // 16,777,216 -> 75,497,472
  bf16*  hb     = (bf16*)(Y);                          // 16,777,216 (dead after qkv GEMM)
  bf16*  wcat_b = (bf16*)(Y + 16777216);               // 17,301,504 (dead after qkv)
  bf16*  wqb_b  = (bf16*)(Y);                          // 18,874,368 (cast after qkv, over hb)
  bf16*  q_a_bf = (bf16*)(Y + 18874368);               // 6,291,456
  bf16*  q_raw  = (bf16*)(Y + 25165824);               // 25,165,824 (over dead wcat)
  bf16*  k2     = (bf16*)(Y);                          // 25,165,824 (after q_b GEMM)
  bf16*  kv_vT  = (bf16*)(Y + 50331648);               // 16,777,216
  float* out_p1 = (float*)(Y);                         // 33,554,432 (after attn)

  // ---- early casts ----
  cast_kernel<<<1024, 256, 0, stream>>>(h2,     hb,     (long long)S * D / 4);
  cast_kernel<<<1024, 256, 0, stream>>>(w_q_a,  wcat_b, (long long)QL * D / 4);
  cast_kernel<<<1024, 256, 0, stream>>>(w_kv_a, wcat_b + (long long)QL * D, (long long)CAT * D / 4);
  cast_kernel<<<1024, 256, 0, stream>>>(w_uk_t, wukb,   (long long)H * NOPE * KVL / 4);
  tcast_kernel<<<dim3(VH / 32, KVL / 32, H), 256, 0, stream>>>(w_uv, wuv_t, KVL, VH);

  // 1+4 merged: qkv partials = hb @ wcat_b^T, mgemm3 256² K-split z=4
  //   grid (ceil(2112/256)=9, 2048/256=8, 4) = 288 blocks; N-tail guarded
  mgemm3<float><<<dim3(9, 8, 4), 512, 0, stream>>>(
      hb, wcat_b, qkv_p, S, NCAT, D / 4, D, D, NCAT,
      (long long)(D / 4), (long long)(D / 4), (long long)S * NCAT);
  // cast w_q_b now (hb dead; region reused)
  cast_kernel<<<1024, 256, 0, stream>>>(w_q_b, wqb_b, (long long)H * QKH * QL / 4);
  // 2. rmsnorm over 4-partial sum (first 1536 cols) -> bf16
  rmsnorm_cast_kernel<<<dim3(S), 256, 0, stream>>>(
      qkv_p, g_q_a, q_a_bf, NCAT, (long long)S * NCAT);
  // 3. q = q_a @ w_q_b^T -> bf16 (mgemm2, 768 blocks)
  mgemm2<bf16><<<dim3(H * QKH / 128, S / 128, 1), 256, 0, stream>>>(
      q_a_bf, wqb_b, q_raw, S, H * QKH, QL, QL, QL, H * QKH, 0, 0, 0);
  // 5. kv post over 4-partial sum (cols 1536..2111) -> kv_cat
  kvpost_kernel<<<dim3(S), 256, 0, stream>>>(
      qkv_p + QL, g_kv_a, cosp, sinp, kv_cat, NCAT, (long long)S * NCAT);
  // cast w_o (qkv_p dead; region reused)
  cast_kernel<<<1024, 256, 0, stream>>>(w_o, wo_b, (long long)D * H * VH / 4);
  // 5b. value-absorb: kv_vT[h] = (kv_c @ w_uv[h])^T  -> bf16 [h][128][S]
  mgemm2<bf16, true><<<dim3(VH / 128, S / 128, H), 256, 0, stream>>>(
      kv_cat, wuv_t, kv_vT, S, VH, KVL, CAT, KVL, S,
      0, (long long)VH * KVL, (long long)VH * S);
  // 6. q prep (nope copy + rope) -> q2 [h][s][192]
  qprep_kernel<<<dim3(S * H / 4), 256, 0, stream>>>(q_raw, cosp, sinp, q2);
  // 7. key-absorb: k2[h][...,0:128] = kv_c @ w_uk[h]^T
  mgemm2<bf16><<<dim3(1, S / 128, H), 256, 0, stream>>>(
      kv_cat, wukb, k2, S, NOPE, KVL, CAT, KVL, CAT2,
      0, (long long)NOPE * KVL, (long long)S * CAT2);
  // 7b. k rope broadcast -> k2[h][...,128:192]
  krope_bcast<<<dim3(S), 256, 0, stream>>>(kv_cat, k2);
  // 8. attention -> ctx bf16 [s][h*128+v]
  attn_mfma13<<<dim3(512), dim3(512), 0, stream>>>(q2, k2, kv_vT, ctx);
  // 10. out = ctx @ w_o^T -> f32, mgemm3 256² K-split z=2
  //     grid (16, 8, 2) = 256 blocks = 1/CU; z=0 -> out, z=1 -> out_p1
  const long long ooff = (long long)(out_p1 - out);
  mgemm3<float><<<dim3(16, 8, 2), 512, 0, stream>>>(
      ctx, wo_b, out, S, D, D / 2, D, D, D,
      (long long)(D / 2), (long long)(D / 2), ooff);
  // 10b. combine: out += out_p1
  add_kernel<<<1024, 256, 0, stream>>>(out, out_p1, (long long)S * D / 4);

  (void)in_sizes; (void)n_in; (void)out_size; (void)ws_size;
}

// Round 11
// 416.786 us; speedup vs baseline: 1.0913x; 1.0020x over previous
//
#include <hip/hip_runtime.h>
#include <hip/hip_bf16.h>

typedef __hip_bfloat16 bf16;
typedef __attribute__((ext_vector_type(8))) short  s16x8;  // 8 bf16 = 4 VGPR (MFMA A/B frag)
typedef __attribute__((ext_vector_type(4))) float  f32x4;  // MFMA C/D frag

static constexpr int S    = 2048;
static constexpr int D    = 4096;
static constexpr int H    = 32;
static constexpr int QL   = 1536;
static constexpr int KVL  = 512;
static constexpr int NOPE = 128;
static constexpr int ROPE = 64;
static constexpr int QKH  = 192;
static constexpr int VH   = 128;
static constexpr int CAT  = 576;
static constexpr int CAT2 = 192;    // absorbed head dim: 128 nope + 64 rope
static constexpr int NCAT = 2112;   // QL + CAT (merged q_a/kv_a GEMM width)
static constexpr float EPS = 1e-6f;

__device__ __forceinline__ void stf(float* p, float v){ *p = v; }
__device__ __forceinline__ void stf(bf16* p, float v){ *p = __float2bfloat16(v); }

__device__ __forceinline__ float wave_sum(float v){
#pragma unroll
  for (int off = 32; off; off >>= 1) v += __shfl_xor(v, off, 64);
  return v;
}

__device__ __forceinline__ void gload16(const bf16* src, unsigned short* dst){
  __builtin_amdgcn_global_load_lds(
      (const __attribute__((address_space(1))) unsigned int*)src,
      (__attribute__((address_space(3))) unsigned int*)dst, 16, 0, 0);
}

// ---------------------------------------------------------------------------
// f32 -> bf16 cast, vectorized
// ---------------------------------------------------------------------------
__global__ __launch_bounds__(256)
void cast_kernel(const float* __restrict__ in, bf16* __restrict__ out, long long n4)
{
  long long i = (long long)blockIdx.x * 256 + threadIdx.x;
  const long long stride = (long long)gridDim.x * 256;
  for (; i < n4; i += stride) {
    float4 v = ((const float4*)in)[i];
    union { bf16 b[4]; uint2 u; } t;
    t.b[0] = __float2bfloat16(v.x); t.b[1] = __float2bfloat16(v.y);
    t.b[2] = __float2bfloat16(v.z); t.b[3] = __float2bfloat16(v.w);
    *(uint2*)(out + i * 4) = t.u;
  }
}

// ---------------------------------------------------------------------------
// f32 add: dst += src (K-split combine for the out GEMM)
// ---------------------------------------------------------------------------
__global__ __launch_bounds__(256)
void add_kernel(float* __restrict__ dst, const float* __restrict__ src, long long n4)
{
  long long i = (long long)blockIdx.x * 256 + threadIdx.x;
  const long long stride = (long long)gridDim.x * 256;
  for (; i < n4; i += stride) {
    float4 a = ((const float4*)dst)[i];
    const float4 b = ((const float4*)src)[i];
    a.x += b.x; a.y += b.y; a.z += b.z; a.w += b.w;
    ((float4*)dst)[i] = a;
  }
}

// ---------------------------------------------------------------------------
// transpose-cast: in f32 [batch][R][C] -> out bf16 [batch][C][R]. 32x32 tiles.
// ---------------------------------------------------------------------------
__global__ __launch_bounds__(256)
void tcast_kernel(const float* __restrict__ in, bf16* __restrict__ out, int R, int C)
{
  const long long b = blockIdx.z;
  in  += b * (long long)R * C;
  out += b * (long long)R * C;
  const int c0 = blockIdx.x * 32, r0 = blockIdx.y * 32;
  __shared__ float t[32][33];
  const int tx = threadIdx.x & 31, ty = threadIdx.x >> 5;
#pragma unroll
  for (int p = 0; p < 4; p++)
    t[ty + p * 8][tx] = in[(long long)(r0 + ty + p * 8) * C + c0 + tx];
  __syncthreads();
#pragma unroll
  for (int p = 0; p < 4; p++)
    out[(long long)(c0 + ty + p * 8) * R + r0 + tx] = __float2bfloat16(t[tx][ty + p * 8]);
}

// ---------------------------------------------------------------------------
// MFMA GEMM v3 (verified R10): 256x256 tile, BK=64, 8 waves, counted-vmcnt
// deep pipeline (T3/T4 essentials).  Raw s_barrier + s_waitcnt vmcnt(8) keeps
// the NEXT tile's 8 global_load_lds in flight ACROSS the barrier.
// EPI=0: C[row*ldc+col] (normal).  EPI=1: ABSORB epilogue -- col<4096 writes
// k2[h=col>>7][row][col&127] (via C, ldc=CAT2 layout), col>=4096 writes
// kv_vT[(col-4096)*S + row] (via C2) -- fuses key-absorb + value-absorb into
// one dispatch (B = [wukb; wuv_t] contiguous, N=8192).
// ---------------------------------------------------------------------------
template<typename TC, int EPI = 0>
__global__ __launch_bounds__(512, 2)
void mgemm3(const bf16* __restrict__ A, const bf16* __restrict__ B, TC* __restrict__ C,
            TC* __restrict__ C2,
            int M, int N, int K, int lda, int ldb, int ldc,
            long long sA, long long sB, long long sC)
{
  A += (long long)blockIdx.z * sA;
  B += (long long)blockIdx.z * sB;
  C += (long long)blockIdx.z * sC;
  __shared__ unsigned short As[2][256 * 64];   // 2 x 32 KB
  __shared__ unsigned short Bs[2][256 * 64];   // 2 x 32 KB
  const int tid = threadIdx.x;
  const int w = tid >> 6;
  const int lane = tid & 63;
  const int l15 = lane & 15, g = lane >> 4;
  const int wr = w >> 2, wc = w & 3;
  const int m0 = blockIdx.y * 256, n0 = blockIdx.x * 256;

  // staging sources: 8 gloads/thread/tile (4 A + 4 B), source col pre-swizzled
  const bf16* asrc[4];
  const bf16* bsrc[4];
#pragma unroll
  for (int j = 0; j < 4; j++) {
    const int f = j * 512 + tid;
    const int row = f >> 3;                 // 0..255
    const int cg = ((f & 7) ^ (row & 7)) * 8;
    asrc[j] = A + (long long)(m0 + row) * lda + cg;
    int br = n0 + row; if (br >= N) br = N - 1;
    bsrc[j] = B + (long long)br * ldb + cg;
  }

  auto stage = [&](int b, int k0) {
#pragma unroll
    for (int j = 0; j < 4; j++) {
      gload16(asrc[j] + k0, &As[b][(j * 512 + w * 64) * 8]);
      gload16(bsrc[j] + k0, &Bs[b][(j * 512 + w * 64) * 8]);
    }
  };

  f32x4 acc[8][4];
#pragma unroll
  for (int i = 0; i < 8; i++)
#pragma unroll
    for (int j = 0; j < 4; j++) acc[i][j] = (f32x4){0.f, 0.f, 0.f, 0.f};

  const int ntk = K >> 6;                   // K-tiles of 64
  stage(0, 0);                              // prologue: tile 0 -> buf 0

  for (int t = 0; t < ntk; ++t) {
    const int b = t & 1;
    asm volatile("" ::: "memory");
    __builtin_amdgcn_s_barrier();           // all waves done reading buf b^1 (tile t-1)
    if (t + 1 < ntk) {
      stage(b ^ 1, (t + 1) << 6);           // issue tile t+1 -> buf b^1
      asm volatile("s_waitcnt vmcnt(8)" ::: "memory");   // tile t's 8 landed; t+1's stay in flight
    } else {
      asm volatile("s_waitcnt vmcnt(0)" ::: "memory");   // final tile: drain
    }
    __builtin_amdgcn_s_barrier();           // all waves' tile-t loads visible
    asm volatile("" ::: "memory");

    const unsigned short* Ab = &As[b][(wr * 128 + l15) * 64];
    const unsigned short* Bb = &Bs[b][(wc * 64 + l15) * 64];
    const int swz = l15 & 7;
#pragma unroll
    for (int kk = 0; kk < 2; ++kk) {
      const int co = (((kk * 4 + g) ^ swz) * 8);
      s16x8 a[8], bb[4];
#pragma unroll
      for (int mt = 0; mt < 8; mt++)
        a[mt] = *(const s16x8*)(Ab + mt * 1024 + co);
#pragma unroll
      for (int nt = 0; nt < 4; nt++)
        bb[nt] = *(const s16x8*)(Bb + nt * 1024 + co);
      __builtin_amdgcn_s_setprio(1);
#pragma unroll
      for (int mt = 0; mt < 8; mt++)
#pragma unroll
        for (int nt = 0; nt < 4; nt++)
          acc[mt][nt] = __builtin_amdgcn_mfma_f32_16x16x32_bf16(a[mt], bb[nt], acc[mt][nt], 0, 0, 0);
      __builtin_amdgcn_s_setprio(0);
    }
  }

  // epilogue (rows always valid: M % 256 == 0)
#pragma unroll
  for (int mt = 0; mt < 8; mt++)
#pragma unroll
    for (int nt = 0; nt < 4; nt++) {
      const int col = n0 + wc * 64 + nt * 16 + l15;
      const int row0 = m0 + wr * 128 + mt * 16 + g * 4;
      if constexpr (EPI == 0) {
        if (col < N) {
#pragma unroll
          for (int r = 0; r < 4; r++)
            stf(C + (long long)(row0 + r) * ldc + col, acc[mt][nt][r]);
        }
      } else {
        if (col < H * NOPE) {               // key-absorb -> k2[h][row][n]
          TC* dst = C + ((long long)(col >> 7) * S + row0) * CAT2 + (col & 127);
#pragma unroll
          for (int r = 0; r < 4; r++)
            stf(dst + (long long)r * CAT2, acc[mt][nt][r]);
        } else {                             // value-absorb -> kv_vT[c'][row]
          TC* dst = C2 + (long long)(col - H * NOPE) * S + row0;
#pragma unroll
          for (int r = 0; r < 4; r++)
            stf(dst + r, acc[mt][nt][r]);
        }
      }
    }
}

// ---------------------------------------------------------------------------
// RMSNorm over SUM of FOUR K-split partials (z-stride poff), N = QL fixed.
// ---------------------------------------------------------------------------
__global__ __launch_bounds__(256)
void rmsnorm_cast_kernel(const float* __restrict__ x, const float* __restrict__ g,
                         bf16* __restrict__ out, int ldx, long long poff)
{
  const int row = blockIdx.x;
  const float* xr = x + (long long)row * ldx;
  float v[6];
  float ss = 0.f;
#pragma unroll
  for (int k = 0; k < 6; k++) {
    const int c = threadIdx.x + (k << 8);
    const float t = xr[c] + xr[c + poff] + xr[c + 2 * poff] + xr[c + 3 * poff];
    v[k] = t; ss += t * t;
  }
  __shared__ float red[4];
  ss = wave_sum(ss);
  if ((threadIdx.x & 63) == 0) red[threadIdx.x >> 6] = ss;
  __syncthreads();
  const float inv = rsqrtf((red[0] + red[1] + red[2] + red[3]) / (float)QL + EPS);
#pragma unroll
  for (int k = 0; k < 6; k++) {
    const int c = threadIdx.x + (k << 8);
    out[(long long)row * QL + c] = __float2bfloat16(v[k] * inv * g[c]);
  }
}

// ---------------------------------------------------------------------------
// kv post over SUM of FOUR K-split partials (row stride ldr, z-stride poff).
// ---------------------------------------------------------------------------
__global__ __launch_bounds__(256)
void kvpost_kernel(const float* __restrict__ kv_raw, const float* __restrict__ g,
                   const float* __restrict__ cosp, const float* __restrict__ sinp,
                   bf16* __restrict__ kv_cat, int ldr, long long poff)
{
  const int s = blockIdx.x;
  const float* row = kv_raw + (long long)s * ldr;
  float v[2];
  float ss = 0.f;
#pragma unroll
  for (int k = 0; k < 2; k++) {
    const int c = threadIdx.x + (k << 8);
    const float t = row[c] + row[c + poff] + row[c + 2 * poff] + row[c + 3 * poff];
    v[k] = t; ss += t * t;
  }
  __shared__ float red[4];
  float ws_ = wave_sum(ss);
  if ((threadIdx.x & 63) == 0) red[threadIdx.x >> 6] = ws_;
  __syncthreads();
  const float inv = rsqrtf((red[0] + red[1] + red[2] + red[3]) / (float)KVL + EPS);
#pragma unroll
  for (int k = 0; k < 2; k++) {
    const int c = threadIdx.x + (k << 8);
    kv_cat[(long long)s * CAT + c] = __float2bfloat16(v[k] * inv * g[c]);
  }
  if (threadIdx.x < 64) {
    const int r = threadIdx.x;
    const int c = KVL + r;
    const float x = row[c] + row[c + poff] + row[c + 2 * poff] + row[c + 3 * poff];
    const float xp = __shfl_xor(x, 32, 64);
    const float rot = (r < 32) ? -xp : xp;
    kv_cat[(long long)s * CAT + KVL + r] =
        __float2bfloat16(x * cosp[s * ROPE + r] + rot * sinp[s * ROPE + r]);
  }
}

// ---------------------------------------------------------------------------
// q prep: q2[h][s][0:128] = q_raw nope cols; q2[h][s][128:192] = rope(q_rope)
// ---------------------------------------------------------------------------
__global__ __launch_bounds__(256)
void qprep_kernel(const bf16* __restrict__ q_raw, const float* __restrict__ cosp,
                  const float* __restrict__ sinp, bf16* __restrict__ q2)
{
  const int wid  = blockIdx.x * 4 + (threadIdx.x >> 6);
  const int lane = threadIdx.x & 63;
  const int s = wid >> 5;
  const int h = wid & 31;
  const bf16* src = q_raw + (long long)s * (H * QKH) + h * QKH;
  bf16* dst = q2 + ((long long)h * S + s) * CAT2;
  ((unsigned int*)dst)[lane] = ((const unsigned int*)src)[lane];
  const float x  = __bfloat162float(src[NOPE + lane]);
  const float xp = __shfl_xor(x, 32, 64);
  const float rot = (lane < 32) ? -xp : xp;
  dst[NOPE + lane] =
      __float2bfloat16(x * cosp[s * ROPE + lane] + rot * sinp[s * ROPE + lane]);
}

// ---------------------------------------------------------------------------
// k rope broadcast: k2[h][s][128+r] = kv_cat[s][512+r] for all heads
// ---------------------------------------------------------------------------
__global__ __launch_bounds__(256)
void krope_bcast(const bf16* __restrict__ kv_cat, bf16* __restrict__ k2)
{
  const int s = blockIdx.x;
  const int h = threadIdx.x >> 3;
  const int i = (threadIdx.x & 7) * 8;
  *(uint4*)(k2 + ((long long)h * S + s) * CAT2 + NOPE + i) =
      *(const uint4*)(kv_cat + (long long)s * CAT + KVL + i);
}

// ---------------------------------------------------------------------------
// MFMA flash attention v14 = v13 compute + counted-vmcnt sync skeleton (the
// R10 mgemm3 pattern): raw s_barrier + per-wave s_waitcnt vmcnt(N) keeps the
// NEXT K/V tile's loads in flight across the barrier instead of the
// __syncthreads vmcnt(0) drain every 32-key tile.  Waves 0-3 issue 3 stage
// loads/tile (extra K chunk), waves 4-7 issue 2 -> vmcnt(3)/vmcnt(2).
// QK^T / softmax / PV / epilogue byte-identical to verified v13.
// ---------------------------------------------------------------------------
__global__ __launch_bounds__(512, 2)
void attn_mfma14(const bf16* __restrict__ q2, const bf16* __restrict__ k2,
                 const bf16* __restrict__ kv_vT, bf16* __restrict__ ctx)
{
  __shared__ unsigned short kkl[2][32 * CAT2];  // 2 x 12,288 B  K tiles (swizzled)
  __shared__ unsigned short vtl[2][128 * 32];   // 2 x  8,192 B  V^T tiles (swizzled)
  __shared__ unsigned short ps[8][16][40];      // 10,240 B per-wave P transpose
  const int tid = threadIdx.x;
  const int bid = blockIdx.x;
  const int h  = bid & 31;
  const int qb = 15 - (bid >> 5);               // heavy blocks dispatched first
  const int w = tid >> 6, lane = tid & 63;
  const int l15 = lane & 15, g = lane >> 4;
  const int wq0 = qb * 128 + w * 16;
  const int rbase = g * 4;
  const float scale = 0.07216878364870322f;     // 1/sqrt(192)

  const bf16* ksrc[2];
#pragma unroll
  for (int j = 0; j < 2; j++) {
    const int f  = j * 512 + ((j == 1) ? (tid & 255) : tid);
    const int r  = f / 24;
    const int cg = ((f % 24) << 4) ^ ((r & 7) << 4);
    ksrc[j] = k2 + ((long long)h * S + r) * CAT2 + (cg >> 1);
  }
  const int vc = tid >> 2;
  const bf16* vsrc = kv_vT + (long long)h * VH * S + (long long)vc * S
                   + (((tid & 3) ^ ((vc >> 1) & 3)) * 8);

  auto stage = [&](int buf, int kbase) {
    gload16(ksrc[0] + (long long)kbase * CAT2, &kkl[buf][(w * 64) * 8]);
    if (tid < 256)
      gload16(ksrc[1] + (long long)kbase * CAT2, &kkl[buf][(512 + w * 64) * 8]);
    gload16(vsrc + kbase, &vtl[buf][(w * 64) * 8]);
  };

  s16x8 qf[6];
  const bf16* qp = q2 + ((long long)h * S + (wq0 + l15)) * CAT2 + g * 8;
#pragma unroll
  for (int ch = 0; ch < 6; ch++) qf[ch] = *(const s16x8*)(qp + ch * 32);

  s16x8 ones;
#pragma unroll
  for (int i = 0; i < 8; i++) ones[i] = (short)0x3F80;

  f32x4 acc[8];
#pragma unroll
  for (int nt = 0; nt < 8; nt++) acc[nt] = (f32x4){0.f, 0.f, 0.f, 0.f};
  f32x4 accl = (f32x4){0.f, 0.f, 0.f, 0.f};
  float mrow[4];
#pragma unroll
  for (int r = 0; r < 4; r++) mrow[r] = -3e38f;

  stage(0, 0);                                  // prologue: tile 0 -> buf 0

  const int ntb = 4 * qb + 4;
  int buf = 0;
  for (int t = 0; t < ntb; t++) {
    const int kbase = t * 32;
    asm volatile("" ::: "memory");
    __builtin_amdgcn_s_barrier();               // all waves done reading buf^1
    if (t + 1 < ntb) {
      stage(buf ^ 1, kbase + 32);               // issue tile t+1 -> buf^1
      if (w < 4) asm volatile("s_waitcnt vmcnt(3)" ::: "memory");  // tile t landed
      else       asm volatile("s_waitcnt vmcnt(2)" ::: "memory");
    } else {
      asm volatile("s_waitcnt vmcnt(0)" ::: "memory");
    }
    __builtin_amdgcn_s_barrier();               // tile t visible to all waves
    asm volatile("" ::: "memory");

    if (kbase <= wq0 + 15) {
      f32x4 st0 = (f32x4){0.f,0.f,0.f,0.f}, st1 = (f32x4){0.f,0.f,0.f,0.f};
      const unsigned short* kb0 = &kkl[buf][l15 * CAT2];
      const int rsw = (l15 & 7) << 4;
#pragma unroll
      for (int ch = 0; ch < 6; ch++) {
        const int cb = ((ch * 64 + g * 16) ^ rsw) >> 1;
        s16x8 b0 = *(const s16x8*)(kb0 + cb);
        s16x8 b1 = *(const s16x8*)(kb0 + 16 * CAT2 + cb);
        st0 = __builtin_amdgcn_mfma_f32_16x16x32_bf16(qf[ch], b0, st0, 0, 0, 0);
        st1 = __builtin_amdgcn_mfma_f32_16x16x32_bf16(qf[ch], b1, st1, 0, 0, 0);
      }
      float p0v[4], p1v[4];
      float pmax = 0.f;
#pragma unroll
      for (int r = 0; r < 4; r++) {
        const int qg = wq0 + rbase + r;
        const bool v0 = (kbase + l15) <= qg, v1 = (kbase + 16 + l15) <= qg;
        const float s0 = st0[r] * scale, s1 = st1[r] * scale;
        const float p0 = v0 ? __expf(s0 - mrow[r]) : 0.f;
        const float p1 = v1 ? __expf(s1 - mrow[r]) : 0.f;
        p0v[r] = p0; p1v[r] = p1;
        pmax = fmaxf(pmax, fmaxf(p0, p1));
      }
      if (__builtin_expect(__any(pmax > 2981.0f), 0)) {   // rare: growth > ~8
#pragma unroll
        for (int r = 0; r < 4; r++) {
          const int qg = wq0 + rbase + r;
          const bool v0 = (kbase + l15) <= qg, v1 = (kbase + 16 + l15) <= qg;
          const float s0 = st0[r] * scale, s1 = st1[r] * scale;
          float tmax = fmaxf(v0 ? s0 : -3e38f, v1 ? s1 : -3e38f);
#pragma unroll
          for (int off = 8; off; off >>= 1) tmax = fmaxf(tmax, __shfl_xor(tmax, off, 64));
          if (tmax > mrow[r] + 8.0f) {
            const float corr = __expf(mrow[r] - tmax);    // 0 on first tile
            mrow[r] = tmax;
#pragma unroll
            for (int nt = 0; nt < 8; nt++) acc[nt][r] *= corr;
            accl[r] *= corr;
            p0v[r] = v0 ? __expf(s0 - mrow[r]) : 0.f;
            p1v[r] = v1 ? __expf(s1 - mrow[r]) : 0.f;
          }
        }
      }
#pragma unroll
      for (int r = 0; r < 4; r++) {
        union { bf16 b; unsigned short u; } c0, c1;
        c0.b = __float2bfloat16(p0v[r]); c1.b = __float2bfloat16(p1v[r]);
        ps[w][rbase + r][l15]      = c0.u;
        ps[w][rbase + r][16 + l15] = c1.u;
      }
      asm volatile("" ::: "memory");   // order ps stores before reads (per-wave)
      s16x8 pa = *(const s16x8*)&ps[w][l15][g * 8];
      const unsigned short* vt = &vtl[buf][l15 * 32 + ((g * 8) ^ (((l15 >> 1) & 3) * 8))];
#pragma unroll
      for (int nt = 0; nt < 8; nt++) {
        s16x8 bv = *(const s16x8*)(vt + nt * 512);
        acc[nt] = __builtin_amdgcn_mfma_f32_16x16x32_bf16(pa, bv, acc[nt], 0, 0, 0);
      }
      accl = __builtin_amdgcn_mfma_f32_16x16x32_bf16(pa, ones, accl, 0, 0, 0);
    }
    buf ^= 1;
  }

  // ---- epilogue: normalize by l, store ctx[s][h*128+v] bf16 ----
#pragma unroll
  for (int r = 0; r < 4; r++) {
    const float inv = 1.f / accl[r];
    bf16* op = ctx + (long long)(wq0 + rbase + r) * (H * VH) + h * VH + l15;
#pragma unroll
    for (int nt = 0; nt < 8; nt++) op[nt * 16] = __float2bfloat16(acc[nt][r] * inv);
  }
}

// ---------------------------------------------------------------------------
extern "C" void kernel_launch(void* const* d_in, const int* in_sizes, int n_in,
                              void* d_out, int out_size, void* d_ws, size_t ws_size,
                              hipStream_t stream)
{
  const float* h2     = (const float*)d_in[0];
  const float* cosp   = (const float*)d_in[1];
  const float* sinp   = (const float*)d_in[2];
  const float* w_q_a  = (const float*)d_in[3];
  const float* g_q_a  = (const float*)d_in[4];
  const float* w_q_b  = (const float*)d_in[5];
  const float* w_kv_a = (const float*)d_in[6];
  const float* g_kv_a = (const float*)d_in[7];
  const float* w_uk_t = (const float*)d_in[8];
  const float* w_uv   = (const float*)d_in[9];
  const float* w_o    = (const float*)d_in[10];
  float* out = (float*)d_out;

  // ---- workspace layout (identical to R9/R10, which passed) ----
  char* ws = (char*)d_ws;
  bf16* wukb   = (bf16*)(ws);                          // 4,194,304  [H][NOPE][KVL]
  bf16* wuv_t  = (bf16*)(ws + 4194304);                // 4,194,304  [H][VH][KVL] (contiguous after wukb)
  bf16* kv_cat = (bf16*)(ws + 8388608);                // 2,359,296
  char* X = ws + 13107200;                             // 75,497,472
  char* Y = X + 75497472;                              // 67,108,864
  float* qkv_p = (float*)(X);                          // [4][2048][2112] f32 (dead after rmsnorm+kvpost)
  bf16*  wo_b  = (bf16*)(X);                           // 33,554,432 (after kvpost)
  bf16*  q2    = (bf16*)(X + 33554432);                // 25,165,824 -> 58,720,256
  bf16*  ctx   = (bf16*)(X + 58720256);                // 16,777,216 -> 75,497,472
  bf16*  hb     = (bf16*)(Y);                          // 16,777,216 (dead after qkv GEMM)
  bf16*  wcat_b = (bf16*)(Y + 16777216);               // 17,301,504 (dead after qkv)
  bf16*  wqb_b  = (bf16*)(Y);                          // 18,874,368 (cast after qkv, over hb)
  bf16*  q_a_bf = (bf16*)(Y + 18874368);               // 6,291,456
  bf16*  q_raw  = (bf16*)(Y + 25165824);               // 25,165,824 (over dead wcat)
  bf16*  k2     = (bf16*)(Y);                          // 25,165,824 (after q_b GEMM)
  bf16*  kv_vT  = (bf16*)(Y + 50331648);               // 16,777,216
  float* out_p1 = (float*)(Y);                         // 33,554,432 (after attn)

  // ---- early casts ----
  cast_kernel<<<1024, 256, 0, stream>>>(h2,     hb,     (long long)S * D / 4);
  cast_kernel<<<1024, 256, 0, stream>>>(w_q_a,  wcat_b, (long long)QL * D / 4);
  cast_kernel<<<1024, 256, 0, stream>>>(w_kv_a, wcat_b + (long long)QL * D, (long long)CAT * D / 4);
  cast_kernel<<<1024, 256, 0, stream>>>(w_uk_t, wukb,   (long long)H * NOPE * KVL / 4);
  tcast_kernel<<<dim3(VH / 32, KVL / 32, H), 256, 0, stream>>>(w_uv, wuv_t, KVL, VH);

  // 1+4 merged: qkv partials = hb @ wcat_b^T, mgemm3 256² K-split z=4
  mgemm3<float><<<dim3(9, 8, 4), 512, 0, stream>>>(
      hb, wcat_b, qkv_p, qkv_p, S, NCAT, D / 4, D, D, NCAT,
      (long long)(D / 4), (long long)(D / 4), (long long)S * NCAT);
  // cast w_q_b now (hb dead; region reused)
  cast_kernel<<<1024, 256, 0, stream>>>(w_q_b, wqb_b, (long long)H * QKH * QL / 4);
  // 2. rmsnorm over 4-partial sum (first 1536 cols) -> bf16
  rmsnorm_cast_kernel<<<dim3(S), 256, 0, stream>>>(
      qkv_p, g_q_a, q_a_bf, NCAT, (long long)S * NCAT);
  // 3. q = q_a @ w_q_b^T -> bf16 (mgemm3: grid 24x8, K=1536)
  mgemm3<bf16><<<dim3(H * QKH / 256, S / 256, 1), 512, 0, stream>>>(
      q_a_bf, wqb_b, q_raw, q_raw, S, H * QKH, QL, QL, QL, H * QKH, 0, 0, 0);
  // 5. kv post over 4-partial sum (cols 1536..2111) -> kv_cat
  kvpost_kernel<<<dim3(S), 256, 0, stream>>>(
      qkv_p + QL, g_kv_a, cosp, sinp, kv_cat, NCAT, (long long)S * NCAT);
  // cast w_o (qkv_p dead; region reused)
  cast_kernel<<<1024, 256, 0, stream>>>(w_o, wo_b, (long long)D * H * VH / 4);
  // 5b+7 merged ABSORB: [k_nope_all | v_all] = kv_c @ [wukb; wuv_t]^T
  //   N=8192, grid 32x8 = 256 blocks = 1/CU; epilogue scatters col<4096 to
  //   k2[h][s][0:128], col>=4096 to kv_vT[h*128+v][s]  (k2 over dead wqb_b)
  mgemm3<bf16, 1><<<dim3(H * (NOPE + VH) / 256, S / 256, 1), 512, 0, stream>>>(
      kv_cat, (const bf16*)ws, k2, kv_vT, S, H * (NOPE + VH), KVL,
      CAT, KVL, 0, 0, 0, 0);
  // 6. q prep (nope copy + rope) -> q2 [h][s][192]  (q_raw dead after this)
  qprep_kernel<<<dim3(S * H / 4), 256, 0, stream>>>(q_raw, cosp, sinp, q2);
  // 7b. k rope broadcast -> k2[h][...,128:192]
  krope_bcast<<<dim3(S), 256, 0, stream>>>(kv_cat, k2);
  // 8. attention (counted-vmcnt skeleton) -> ctx bf16 [s][h*128+v]
  attn_mfma14<<<dim3(512), dim3(512), 0, stream>>>(q2, k2, kv_vT, ctx);
  // 10. out = ctx @ w_o^T -> f32, mgemm3 256² K-split z=2
  const long long ooff = (long long)(out_p1 - out);
  mgemm3<float><<<dim3(16, 8, 2), 512, 0, stream>>>(
      ctx, wo_b, out, out, S, D, D / 2, D, D, D,
      (long long)(D / 2), (long long)(D / 2), ooff);
  // 10b. combine: out += out_p1
  add_kernel<<<1024, 256, 0, stream>>>(out, out_p1, (long long)S * D / 4);

  (void)in_sizes; (void)n_in; (void)out_size; (void)ws_size;
}

// Round 12
// 399.550 us; speedup vs baseline: 1.1384x; 1.0431x over previous
//
#include <hip/hip_runtime.h>
#include <hip/hip_bf16.h>

typedef __hip_bfloat16 bf16;
typedef __attribute__((ext_vector_type(8))) short  s16x8;  // 8 bf16 = 4 VGPR (MFMA A/B frag)
typedef __attribute__((ext_vector_type(4))) float  f32x4;  // MFMA C/D frag

static constexpr int S    = 2048;
static constexpr int D    = 4096;
static constexpr int H    = 32;
static constexpr int QL   = 1536;
static constexpr int KVL  = 512;
static constexpr int NOPE = 128;
static constexpr int ROPE = 64;
static constexpr int QKH  = 192;
static constexpr int VH   = 128;
static constexpr int CAT  = 576;
static constexpr int CAT2 = 192;    // absorbed head dim: 128 nope + 64 rope
static constexpr int NCAT = 2112;   // QL + CAT (merged q_a/kv_a GEMM width)
static constexpr float EPS = 1e-6f;

__device__ __forceinline__ void stf(float* p, float v){ *p = v; }
__device__ __forceinline__ void stf(bf16* p, float v){ *p = __float2bfloat16(v); }

__device__ __forceinline__ float wave_sum(float v){
#pragma unroll
  for (int off = 32; off; off >>= 1) v += __shfl_xor(v, off, 64);
  return v;
}

__device__ __forceinline__ void gload16(const bf16* src, unsigned short* dst){
  __builtin_amdgcn_global_load_lds(
      (const __attribute__((address_space(1))) unsigned int*)src,
      (__attribute__((address_space(3))) unsigned int*)dst, 16, 0, 0);
}

// ---------------------------------------------------------------------------
// f32 -> bf16 cast, vectorized
// ---------------------------------------------------------------------------
__global__ __launch_bounds__(256)
void cast_kernel(const float* __restrict__ in, bf16* __restrict__ out, long long n4)
{
  long long i = (long long)blockIdx.x * 256 + threadIdx.x;
  const long long stride = (long long)gridDim.x * 256;
  for (; i < n4; i += stride) {
    float4 v = ((const float4*)in)[i];
    union { bf16 b[4]; uint2 u; } t;
    t.b[0] = __float2bfloat16(v.x); t.b[1] = __float2bfloat16(v.y);
    t.b[2] = __float2bfloat16(v.z); t.b[3] = __float2bfloat16(v.w);
    *(uint2*)(out + i * 4) = t.u;
  }
}

// ---------------------------------------------------------------------------
// f32 add: dst += src (K-split combine for the out GEMM)
// ---------------------------------------------------------------------------
__global__ __launch_bounds__(256)
void add_kernel(float* __restrict__ dst, const float* __restrict__ src, long long n4)
{
  long long i = (long long)blockIdx.x * 256 + threadIdx.x;
  const long long stride = (long long)gridDim.x * 256;
  for (; i < n4; i += stride) {
    float4 a = ((const float4*)dst)[i];
    const float4 b = ((const float4*)src)[i];
    a.x += b.x; a.y += b.y; a.z += b.z; a.w += b.w;
    ((float4*)dst)[i] = a;
  }
}

// ---------------------------------------------------------------------------
// transpose-cast: in f32 [batch][R][C] -> out bf16 [batch][C][R]. 32x32 tiles.
// ---------------------------------------------------------------------------
__global__ __launch_bounds__(256)
void tcast_kernel(const float* __restrict__ in, bf16* __restrict__ out, int R, int C)
{
  const long long b = blockIdx.z;
  in  += b * (long long)R * C;
  out += b * (long long)R * C;
  const int c0 = blockIdx.x * 32, r0 = blockIdx.y * 32;
  __shared__ float t[32][33];
  const int tx = threadIdx.x & 31, ty = threadIdx.x >> 5;
#pragma unroll
  for (int p = 0; p < 4; p++)
    t[ty + p * 8][tx] = in[(long long)(r0 + ty + p * 8) * C + c0 + tx];
  __syncthreads();
#pragma unroll
  for (int p = 0; p < 4; p++)
    out[(long long)(c0 + ty + p * 8) * R + r0 + tx] = __float2bfloat16(t[tx][ty + p * 8]);
}

// ---------------------------------------------------------------------------
// MFMA GEMM v3 (verified R10/R11): 256x256 tile, BK=64, 8 waves, counted-vmcnt
// deep pipeline.  Raw s_barrier + s_waitcnt vmcnt(8) keeps the NEXT tile's 8
// global_load_lds in flight ACROSS the barrier.
// EPI=0: C[row*ldc+col].  EPI=1: ABSORB epilogue (verified R11) -- col<4096
// writes k2[h=col>>7][row][col&127], col>=4096 writes kv_vT[(col-4096)*S+row].
// ---------------------------------------------------------------------------
template<typename TC, int EPI = 0>
__global__ __launch_bounds__(512, 2)
void mgemm3(const bf16* __restrict__ A, const bf16* __restrict__ B, TC* __restrict__ C,
            TC* __restrict__ C2,
            int M, int N, int K, int lda, int ldb, int ldc,
            long long sA, long long sB, long long sC)
{
  A += (long long)blockIdx.z * sA;
  B += (long long)blockIdx.z * sB;
  C += (long long)blockIdx.z * sC;
  __shared__ unsigned short As[2][256 * 64];   // 2 x 32 KB
  __shared__ unsigned short Bs[2][256 * 64];   // 2 x 32 KB
  const int tid = threadIdx.x;
  const int w = tid >> 6;
  const int lane = tid & 63;
  const int l15 = lane & 15, g = lane >> 4;
  const int wr = w >> 2, wc = w & 3;
  const int m0 = blockIdx.y * 256, n0 = blockIdx.x * 256;

  // staging sources: 8 gloads/thread/tile (4 A + 4 B), source col pre-swizzled
  const bf16* asrc[4];
  const bf16* bsrc[4];
#pragma unroll
  for (int j = 0; j < 4; j++) {
    const int f = j * 512 + tid;
    const int row = f >> 3;                 // 0..255
    const int cg = ((f & 7) ^ (row & 7)) * 8;
    asrc[j] = A + (long long)(m0 + row) * lda + cg;
    int br = n0 + row; if (br >= N) br = N - 1;
    bsrc[j] = B + (long long)br * ldb + cg;
  }

  auto stage = [&](int b, int k0) {
#pragma unroll
    for (int j = 0; j < 4; j++) {
      gload16(asrc[j] + k0, &As[b][(j * 512 + w * 64) * 8]);
      gload16(bsrc[j] + k0, &Bs[b][(j * 512 + w * 64) * 8]);
    }
  };

  f32x4 acc[8][4];
#pragma unroll
  for (int i = 0; i < 8; i++)
#pragma unroll
    for (int j = 0; j < 4; j++) acc[i][j] = (f32x4){0.f, 0.f, 0.f, 0.f};

  const int ntk = K >> 6;                   // K-tiles of 64
  stage(0, 0);                              // prologue: tile 0 -> buf 0

  for (int t = 0; t < ntk; ++t) {
    const int b = t & 1;
    asm volatile("" ::: "memory");
    __builtin_amdgcn_s_barrier();           // all waves done reading buf b^1 (tile t-1)
    if (t + 1 < ntk) {
      stage(b ^ 1, (t + 1) << 6);           // issue tile t+1 -> buf b^1
      asm volatile("s_waitcnt vmcnt(8)" ::: "memory");   // tile t's 8 landed; t+1's stay in flight
    } else {
      asm volatile("s_waitcnt vmcnt(0)" ::: "memory");   // final tile: drain
    }
    __builtin_amdgcn_s_barrier();           // all waves' tile-t loads visible
    asm volatile("" ::: "memory");

    const unsigned short* Ab = &As[b][(wr * 128 + l15) * 64];
    const unsigned short* Bb = &Bs[b][(wc * 64 + l15) * 64];
    const int swz = l15 & 7;
#pragma unroll
    for (int kk = 0; kk < 2; ++kk) {
      const int co = (((kk * 4 + g) ^ swz) * 8);
      s16x8 a[8], bb[4];
#pragma unroll
      for (int mt = 0; mt < 8; mt++)
        a[mt] = *(const s16x8*)(Ab + mt * 1024 + co);
#pragma unroll
      for (int nt = 0; nt < 4; nt++)
        bb[nt] = *(const s16x8*)(Bb + nt * 1024 + co);
      __builtin_amdgcn_s_setprio(1);
#pragma unroll
      for (int mt = 0; mt < 8; mt++)
#pragma unroll
        for (int nt = 0; nt < 4; nt++)
          acc[mt][nt] = __builtin_amdgcn_mfma_f32_16x16x32_bf16(a[mt], bb[nt], acc[mt][nt], 0, 0, 0);
      __builtin_amdgcn_s_setprio(0);
    }
  }

  // epilogue (rows always valid: M % 256 == 0)
#pragma unroll
  for (int mt = 0; mt < 8; mt++)
#pragma unroll
    for (int nt = 0; nt < 4; nt++) {
      const int col = n0 + wc * 64 + nt * 16 + l15;
      const int row0 = m0 + wr * 128 + mt * 16 + g * 4;
      if constexpr (EPI == 0) {
        if (col < N) {
#pragma unroll
          for (int r = 0; r < 4; r++)
            stf(C + (long long)(row0 + r) * ldc + col, acc[mt][nt][r]);
        }
      } else {
        if (col < H * NOPE) {               // key-absorb -> k2[h][row][n]
          TC* dst = C + ((long long)(col >> 7) * S + row0) * CAT2 + (col & 127);
#pragma unroll
          for (int r = 0; r < 4; r++)
            stf(dst + (long long)r * CAT2, acc[mt][nt][r]);
        } else {                             // value-absorb -> kv_vT[c'][row]
          TC* dst = C2 + (long long)(col - H * NOPE) * S + row0;
#pragma unroll
          for (int r = 0; r < 4; r++)
            stf(dst + r, acc[mt][nt][r]);
        }
      }
    }
}

// ---------------------------------------------------------------------------
// RMSNorm over SUM of FOUR K-split partials (z-stride poff), N = QL fixed.
// ---------------------------------------------------------------------------
__global__ __launch_bounds__(256)
void rmsnorm_cast_kernel(const float* __restrict__ x, const float* __restrict__ g,
                         bf16* __restrict__ out, int ldx, long long poff)
{
  const int row = blockIdx.x;
  const float* xr = x + (long long)row * ldx;
  float v[6];
  float ss = 0.f;
#pragma unroll
  for (int k = 0; k < 6; k++) {
    const int c = threadIdx.x + (k << 8);
    const float t = xr[c] + xr[c + poff] + xr[c + 2 * poff] + xr[c + 3 * poff];
    v[k] = t; ss += t * t;
  }
  __shared__ float red[4];
  ss = wave_sum(ss);
  if ((threadIdx.x & 63) == 0) red[threadIdx.x >> 6] = ss;
  __syncthreads();
  const float inv = rsqrtf((red[0] + red[1] + red[2] + red[3]) / (float)QL + EPS);
#pragma unroll
  for (int k = 0; k < 6; k++) {
    const int c = threadIdx.x + (k << 8);
    out[(long long)row * QL + c] = __float2bfloat16(v[k] * inv * g[c]);
  }
}

// ---------------------------------------------------------------------------
// kv post over SUM of FOUR K-split partials (row stride ldr, z-stride poff).
// ---------------------------------------------------------------------------
__global__ __launch_bounds__(256)
void kvpost_kernel(const float* __restrict__ kv_raw, const float* __restrict__ g,
                   const float* __restrict__ cosp, const float* __restrict__ sinp,
                   bf16* __restrict__ kv_cat, int ldr, long long poff)
{
  const int s = blockIdx.x;
  const float* row = kv_raw + (long long)s * ldr;
  float v[2];
  float ss = 0.f;
#pragma unroll
  for (int k = 0; k < 2; k++) {
    const int c = threadIdx.x + (k << 8);
    const float t = row[c] + row[c + poff] + row[c + 2 * poff] + row[c + 3 * poff];
    v[k] = t; ss += t * t;
  }
  __shared__ float red[4];
  float ws_ = wave_sum(ss);
  if ((threadIdx.x & 63) == 0) red[threadIdx.x >> 6] = ws_;
  __syncthreads();
  const float inv = rsqrtf((red[0] + red[1] + red[2] + red[3]) / (float)KVL + EPS);
#pragma unroll
  for (int k = 0; k < 2; k++) {
    const int c = threadIdx.x + (k << 8);
    kv_cat[(long long)s * CAT + c] = __float2bfloat16(v[k] * inv * g[c]);
  }
  if (threadIdx.x < 64) {
    const int r = threadIdx.x;
    const int c = KVL + r;
    const float x = row[c] + row[c + poff] + row[c + 2 * poff] + row[c + 3 * poff];
    const float xp = __shfl_xor(x, 32, 64);
    const float rot = (r < 32) ? -xp : xp;
    kv_cat[(long long)s * CAT + KVL + r] =
        __float2bfloat16(x * cosp[s * ROPE + r] + rot * sinp[s * ROPE + r]);
  }
}

// ---------------------------------------------------------------------------
// q prep: q2[h][s][0:128] = q_raw nope cols; q2[h][s][128:192] = rope(q_rope)
// ---------------------------------------------------------------------------
__global__ __launch_bounds__(256)
void qprep_kernel(const bf16* __restrict__ q_raw, const float* __restrict__ cosp,
                  const float* __restrict__ sinp, bf16* __restrict__ q2)
{
  const int wid  = blockIdx.x * 4 + (threadIdx.x >> 6);
  const int lane = threadIdx.x & 63;
  const int s = wid >> 5;
  const int h = wid & 31;
  const bf16* src = q_raw + (long long)s * (H * QKH) + h * QKH;
  bf16* dst = q2 + ((long long)h * S + s) * CAT2;
  ((unsigned int*)dst)[lane] = ((const unsigned int*)src)[lane];
  const float x  = __bfloat162float(src[NOPE + lane]);
  const float xp = __shfl_xor(x, 32, 64);
  const float rot = (lane < 32) ? -xp : xp;
  dst[NOPE + lane] =
      __float2bfloat16(x * cosp[s * ROPE + lane] + rot * sinp[s * ROPE + lane]);
}

// ---------------------------------------------------------------------------
// k rope broadcast: k2[h][s][128+r] = kv_cat[s][512+r] for all heads
// ---------------------------------------------------------------------------
__global__ __launch_bounds__(256)
void krope_bcast(const bf16* __restrict__ kv_cat, bf16* __restrict__ k2)
{
  const int s = blockIdx.x;
  const int h = threadIdx.x >> 3;
  const int i = (threadIdx.x & 7) * 8;
  *(uint4*)(k2 + ((long long)h * S + s) * CAT2 + NOPE + i) =
      *(const uint4*)(kv_cat + (long long)s * CAT + KVL + i);
}

// ---------------------------------------------------------------------------
// MFMA flash attention v13 (verified R4-R10, 81 us): key+value absorbed,
// head dim 192, cheap overflow-detect softmax, stage-before-compute +
// single __syncthreads skeleton.  (R11's counted-vmcnt skeleton REGRESSED
// 81->97 us -- attn's TLP already hides latency; reverted.)
// ---------------------------------------------------------------------------
__global__ __launch_bounds__(512, 2)
void attn_mfma13(const bf16* __restrict__ q2, const bf16* __restrict__ k2,
                 const bf16* __restrict__ kv_vT, bf16* __restrict__ ctx)
{
  __shared__ unsigned short kkl[2][32 * CAT2];  // 2 x 12,288 B  K tiles (swizzled)
  __shared__ unsigned short vtl[2][128 * 32];   // 2 x  8,192 B  V^T tiles (swizzled)
  __shared__ unsigned short ps[8][16][40];      // 10,240 B per-wave P transpose
  const int tid = threadIdx.x;
  const int bid = blockIdx.x;
  const int h  = bid & 31;
  const int qb = 15 - (bid >> 5);               // heavy blocks dispatched first
  const int w = tid >> 6, lane = tid & 63;
  const int l15 = lane & 15, g = lane >> 4;
  const int wq0 = qb * 128 + w * 16;
  const int rbase = g * 4;
  const float scale = 0.07216878364870322f;     // 1/sqrt(192)

  const bf16* ksrc[2];
#pragma unroll
  for (int j = 0; j < 2; j++) {
    const int f  = j * 512 + ((j == 1) ? (tid & 255) : tid);
    const int r  = f / 24;
    const int cg = ((f % 24) << 4) ^ ((r & 7) << 4);
    ksrc[j] = k2 + ((long long)h * S + r) * CAT2 + (cg >> 1);
  }
  const int vc = tid >> 2;
  const bf16* vsrc = kv_vT + (long long)h * VH * S + (long long)vc * S
                   + (((tid & 3) ^ ((vc >> 1) & 3)) * 8);

  auto stage = [&](int buf, int kbase) {
    gload16(ksrc[0] + (long long)kbase * CAT2, &kkl[buf][(w * 64) * 8]);
    if (tid < 256)
      gload16(ksrc[1] + (long long)kbase * CAT2, &kkl[buf][(512 + w * 64) * 8]);
    gload16(vsrc + kbase, &vtl[buf][(w * 64) * 8]);
  };

  s16x8 qf[6];
  const bf16* qp = q2 + ((long long)h * S + (wq0 + l15)) * CAT2 + g * 8;
#pragma unroll
  for (int ch = 0; ch < 6; ch++) qf[ch] = *(const s16x8*)(qp + ch * 32);

  s16x8 ones;
#pragma unroll
  for (int i = 0; i < 8; i++) ones[i] = (short)0x3F80;

  f32x4 acc[8];
#pragma unroll
  for (int nt = 0; nt < 8; nt++) acc[nt] = (f32x4){0.f, 0.f, 0.f, 0.f};
  f32x4 accl = (f32x4){0.f, 0.f, 0.f, 0.f};
  float mrow[4];
#pragma unroll
  for (int r = 0; r < 4; r++) mrow[r] = -3e38f;

  stage(0, 0);
  __syncthreads();

  const int ntb = 4 * qb + 4;
  int buf = 0;
  for (int t = 0; t < ntb; t++) {
    const int kbase = t * 32;
    if (t + 1 < ntb) stage(buf ^ 1, kbase + 32);   // overlap with compute(t)
    if (kbase <= wq0 + 15) {
      f32x4 st0 = (f32x4){0.f,0.f,0.f,0.f}, st1 = (f32x4){0.f,0.f,0.f,0.f};
      const unsigned short* kb0 = &kkl[buf][l15 * CAT2];
      const int rsw = (l15 & 7) << 4;
#pragma unroll
      for (int ch = 0; ch < 6; ch++) {
        const int cb = ((ch * 64 + g * 16) ^ rsw) >> 1;
        s16x8 b0 = *(const s16x8*)(kb0 + cb);
        s16x8 b1 = *(const s16x8*)(kb0 + 16 * CAT2 + cb);
        st0 = __builtin_amdgcn_mfma_f32_16x16x32_bf16(qf[ch], b0, st0, 0, 0, 0);
        st1 = __builtin_amdgcn_mfma_f32_16x16x32_bf16(qf[ch], b1, st1, 0, 0, 0);
      }
      float p0v[4], p1v[4];
      float pmax = 0.f;
#pragma unroll
      for (int r = 0; r < 4; r++) {
        const int qg = wq0 + rbase + r;
        const bool v0 = (kbase + l15) <= qg, v1 = (kbase + 16 + l15) <= qg;
        const float s0 = st0[r] * scale, s1 = st1[r] * scale;
        const float p0 = v0 ? __expf(s0 - mrow[r]) : 0.f;
        const float p1 = v1 ? __expf(s1 - mrow[r]) : 0.f;
        p0v[r] = p0; p1v[r] = p1;
        pmax = fmaxf(pmax, fmaxf(p0, p1));
      }
      if (__builtin_expect(__any(pmax > 2981.0f), 0)) {   // rare: growth > ~8
#pragma unroll
        for (int r = 0; r < 4; r++) {
          const int qg = wq0 + rbase + r;
          const bool v0 = (kbase + l15) <= qg, v1 = (kbase + 16 + l15) <= qg;
          const float s0 = st0[r] * scale, s1 = st1[r] * scale;
          float tmax = fmaxf(v0 ? s0 : -3e38f, v1 ? s1 : -3e38f);
#pragma unroll
          for (int off = 8; off; off >>= 1) tmax = fmaxf(tmax, __shfl_xor(tmax, off, 64));
          if (tmax > mrow[r] + 8.0f) {
            const float corr = __expf(mrow[r] - tmax);    // 0 on first tile
            mrow[r] = tmax;
#pragma unroll
            for (int nt = 0; nt < 8; nt++) acc[nt][r] *= corr;
            accl[r] *= corr;
            p0v[r] = v0 ? __expf(s0 - mrow[r]) : 0.f;
            p1v[r] = v1 ? __expf(s1 - mrow[r]) : 0.f;
          }
        }
      }
#pragma unroll
      for (int r = 0; r < 4; r++) {
        union { bf16 b; unsigned short u; } c0, c1;
        c0.b = __float2bfloat16(p0v[r]); c1.b = __float2bfloat16(p1v[r]);
        ps[w][rbase + r][l15]      = c0.u;
        ps[w][rbase + r][16 + l15] = c1.u;
      }
      asm volatile("" ::: "memory");   // order ps stores before reads (per-wave)
      s16x8 pa = *(const s16x8*)&ps[w][l15][g * 8];
      const unsigned short* vt = &vtl[buf][l15 * 32 + ((g * 8) ^ (((l15 >> 1) & 3) * 8))];
#pragma unroll
      for (int nt = 0; nt < 8; nt++) {
        s16x8 bv = *(const s16x8*)(vt + nt * 512);
        acc[nt] = __builtin_amdgcn_mfma_f32_16x16x32_bf16(pa, bv, acc[nt], 0, 0, 0);
      }
      accl = __builtin_amdgcn_mfma_f32_16x16x32_bf16(pa, ones, accl, 0, 0, 0);
    }
    __syncthreads();   // drains stage(t+1) loads + all waves done with buf
    buf ^= 1;
  }

  // ---- epilogue: normalize by l, store ctx[s][h*128+v] bf16 ----
#pragma unroll
  for (int r = 0; r < 4; r++) {
    const float inv = 1.f / accl[r];
    bf16* op = ctx + (long long)(wq0 + rbase + r) * (H * VH) + h * VH + l15;
#pragma unroll
    for (int nt = 0; nt < 8; nt++) op[nt * 16] = __float2bfloat16(acc[nt][r] * inv);
  }
}

// ---------------------------------------------------------------------------
extern "C" void kernel_launch(void* const* d_in, const int* in_sizes, int n_in,
                              void* d_out, int out_size, void* d_ws, size_t ws_size,
                              hipStream_t stream)
{
  const float* h2     = (const float*)d_in[0];
  const float* cosp   = (const float*)d_in[1];
  const float* sinp   = (const float*)d_in[2];
  const float* w_q_a  = (const float*)d_in[3];
  const float* g_q_a  = (const float*)d_in[4];
  const float* w_q_b  = (const float*)d_in[5];
  const float* w_kv_a = (const float*)d_in[6];
  const float* g_kv_a = (const float*)d_in[7];
  const float* w_uk_t = (const float*)d_in[8];
  const float* w_uv   = (const float*)d_in[9];
  const float* w_o    = (const float*)d_in[10];
  float* out = (float*)d_out;

  // ---- workspace layout (identical to R10/R11, which passed) ----
  char* ws = (char*)d_ws;
  bf16* wukb   = (bf16*)(ws);                          // 4,194,304  [H][NOPE][KVL]
  bf16* wuv_t  = (bf16*)(ws + 4194304);                // 4,194,304  [H][VH][KVL] (contiguous after wukb)
  bf16* kv_cat = (bf16*)(ws + 8388608);                // 2,359,296
  char* X = ws + 13107200;                             // 75,497,472
  char* Y = X + 75497472;                              // 67,108,864
  float* qkv_p = (float*)(X);                          // [4][2048][2112] f32 (dead after rmsnorm+kvpost)
  bf16*  wo_b  = (bf16*)(X);                           // 33,554,432 (after kvpost)
  bf16*  q2    = (bf16*)(X + 33554432);                // 25,165,824 -> 58,720,256
  bf16*  ctx   = (bf16*)(X + 58720256);                // 16,777,216 -> 75,497,472
  bf16*  hb     = (bf16*)(Y);                          // 16,777,216 (dead after qkv GEMM)
  bf16*  wcat_b = (bf16*)(Y + 16777216);               // 17,301,504 (dead after qkv)
  bf16*  wqb_b  = (bf16*)(Y);                          // 18,874,368 (cast after qkv, over hb)
  bf16*  q_a_bf = (bf16*)(Y + 18874368);               // 6,291,456
  bf16*  q_raw  = (bf16*)(Y + 25165824);               // 25,165,824 (over dead wcat)
  bf16*  k2     = (bf16*)(Y);                          // 25,165,824 (after q_b GEMM)
  bf16*  kv_vT  = (bf16*)(Y + 50331648);               // 16,777,216
  float* out_p1 = (float*)(Y);                         // 33,554,432 (after attn)

  // ---- early casts ----
  cast_kernel<<<1024, 256, 0, stream>>>(h2,     hb,     (long long)S * D / 4);
  cast_kernel<<<1024, 256, 0, stream>>>(w_q_a,  wcat_b, (long long)QL * D / 4);
  cast_kernel<<<1024, 256, 0, stream>>>(w_kv_a, wcat_b + (long long)QL * D, (long long)CAT * D / 4);
  cast_kernel<<<1024, 256, 0, stream>>>(w_uk_t, wukb,   (long long)H * NOPE * KVL / 4);
  tcast_kernel<<<dim3(VH / 32, KVL / 32, H), 256, 0, stream>>>(w_uv, wuv_t, KVL, VH);

  // 1+4 merged: qkv partials = hb @ wcat_b^T, mgemm3 256² K-split z=4
  mgemm3<float><<<dim3(9, 8, 4), 512, 0, stream>>>(
      hb, wcat_b, qkv_p, qkv_p, S, NCAT, D / 4, D, D, NCAT,
      (long long)(D / 4), (long long)(D / 4), (long long)S * NCAT);
  // cast w_q_b now (hb dead; region reused)
  cast_kernel<<<1024, 256, 0, stream>>>(w_q_b, wqb_b, (long long)H * QKH * QL / 4);
  // 2. rmsnorm over 4-partial sum (first 1536 cols) -> bf16
  rmsnorm_cast_kernel<<<dim3(S), 256, 0, stream>>>(
      qkv_p, g_q_a, q_a_bf, NCAT, (long long)S * NCAT);
  // 3. q = q_a @ w_q_b^T -> bf16 (mgemm3: grid 24x8, K=1536)
  mgemm3<bf16><<<dim3(H * QKH / 256, S / 256, 1), 512, 0, stream>>>(
      q_a_bf, wqb_b, q_raw, q_raw, S, H * QKH, QL, QL, QL, H * QKH, 0, 0, 0);
  // 5. kv post over 4-partial sum (cols 1536..2111) -> kv_cat
  kvpost_kernel<<<dim3(S), 256, 0, stream>>>(
      qkv_p + QL, g_kv_a, cosp, sinp, kv_cat, NCAT, (long long)S * NCAT);
  // cast w_o (qkv_p dead; region reused)
  cast_kernel<<<1024, 256, 0, stream>>>(w_o, wo_b, (long long)D * H * VH / 4);
  // 5b+7 merged ABSORB: [k_nope_all | v_all] = kv_c @ [wukb; wuv_t]^T
  //   N=8192, grid 32x8 = 256 blocks = 1/CU; epilogue scatters col<4096 to
  //   k2[h][s][0:128], col>=4096 to kv_vT[h*128+v][s]  (k2 over dead wqb_b)
  mgemm3<bf16, 1><<<dim3(H * (NOPE + VH) / 256, S / 256, 1), 512, 0, stream>>>(
      kv_cat, (const bf16*)ws, k2, kv_vT, S, H * (NOPE + VH), KVL,
      CAT, KVL, 0, 0, 0, 0);
  // 6. q prep (nope copy + rope) -> q2 [h][s][192]  (q_raw dead after this)
  qprep_kernel<<<dim3(S * H / 4), 256, 0, stream>>>(q_raw, cosp, sinp, q2);
  // 7b. k rope broadcast -> k2[h][...,128:192]
  krope_bcast<<<dim3(S), 256, 0, stream>>>(kv_cat, k2);
  // 8. attention (verified v13 skeleton) -> ctx bf16 [s][h*128+v]
  attn_mfma13<<<dim3(512), dim3(512), 0, stream>>>(q2, k2, kv_vT, ctx);
  // 10. out = ctx @ w_o^T -> f32, mgemm3 256² K-split z=2
  const long long ooff = (long long)(out_p1 - out);
  mgemm3<float><<<dim3(16, 8, 2), 512, 0, stream>>>(
      ctx, wo_b, out, out, S, D, D / 2, D, D, D,
      (long long)(D / 2), (long long)(D / 2), ooff);
  // 10b. combine: out += out_p1
  add_kernel<<<1024, 256, 0, stream>>>(out, out_p1, (long long)S * D / 4);

  (void)in_sizes; (void)n_in; (void)out_size; (void)ws_size;
}